// Round 1
// baseline (3261.782 us; speedup 1.0000x reference)
//
#include <hip/hip_runtime.h>
#include <math.h>

#define CTH 8
#define CTW 32
#define CCK 8

// ---------------- weight transpose: w[oc][ci][k9] -> wt[ci*9+k9][oc] ----------------
__global__ __launch_bounds__(256)
void wtrans_kernel(const float* __restrict__ w, float* __restrict__ o, int COUT, int CIN) {
    int i = blockIdx.x * 256 + threadIdx.x;
    int n = COUT * CIN * 9;
    if (i >= n) return;
    int oc  = i / (CIN * 9);
    int rem = i - oc * (CIN * 9);   // ci*9 + k
    o[(size_t)rem * COUT + oc] = w[i];
}

// ---------------- direct 3x3 conv, pad=1 ----------------
// FUSE: 0 = plain load, 1 = relu(in), 2 = in * in2
template<int CIN, bool RELU_OUT, int FUSE>
__global__ __launch_bounds__(256, 4)
void conv3x3_kernel(const float* __restrict__ in, const float* __restrict__ in2,
                    const float* __restrict__ wt, const float* __restrict__ bias,
                    float* __restrict__ out, int COUT, int ocBlocks, int H, int W)
{
    __shared__ float s_in[CCK][CTH + 2][CTW + 4];  // row stride 36 floats (144B, 16B aligned)
    __shared__ float s_w[CCK][9][32];

    const int tid  = threadIdx.x;
    const int bz   = blockIdx.z;
    const int b    = bz / ocBlocks;
    const int ocb  = bz - b * ocBlocks;
    const int row0 = blockIdx.y * CTH;
    const int col0 = blockIdx.x * CTW;
    const int lane = tid & 63;
    const int wv   = tid >> 6;          // 0..3 oc sub-group
    const int r    = lane >> 3;         // 0..7
    const int colb = (lane & 7) << 2;   // 0,4,...,28

    float acc[8][4];
#pragma unroll
    for (int o = 0; o < 8; ++o)
#pragma unroll
        for (int p = 0; p < 4; ++p) acc[o][p] = 0.f;

    const size_t HW = (size_t)H * W;
    const float* inb  = in  + (size_t)b * CIN * HW;
    const float* in2b = (FUSE == 2) ? (in2 + (size_t)b * CIN * HW) : nullptr;

    for (int c0 = 0; c0 < CIN; c0 += CCK) {
        // ---- stage input tile (with zero padding at borders) ----
        for (int idx = tid; idx < CCK * (CTH + 2) * (CTW + 2); idx += 256) {
            int ci  = idx / ((CTH + 2) * (CTW + 2));
            int rem = idx - ci * ((CTH + 2) * (CTW + 2));
            int rr  = rem / (CTW + 2);
            int cc  = rem - rr * (CTW + 2);
            int gy  = row0 - 1 + rr;
            int gx  = col0 - 1 + cc;
            float v = 0.f;
            if (gy >= 0 && gy < H && gx >= 0 && gx < W) {
                size_t gi = (size_t)(c0 + ci) * HW + (size_t)gy * W + gx;
                v = inb[gi];
                if (FUSE == 1) v = fmaxf(v, 0.f);
                if (FUSE == 2) v *= in2b[gi];
            }
            s_in[ci][rr][cc] = v;
        }
        // ---- stage weights: wt[(ci*9+k)*COUT + oc] -> s_w[ci][k][oc32] ----
        for (int idx = tid; idx < CCK * 9 * 32; idx += 256) {
            int ci  = idx / 288;
            int rem = idx - ci * 288;
            int k   = rem >> 5;
            int oc  = rem & 31;
            int oco = ocb * 32 + oc;
            float wval = 0.f;
            if (oco < COUT) wval = wt[(size_t)((c0 + ci) * 9 + k) * COUT + oco];
            s_w[ci][k][oc] = wval;
        }
        __syncthreads();

        for (int ci = 0; ci < CCK; ++ci) {
            float a[3][6];
#pragma unroll
            for (int ky = 0; ky < 3; ++ky) {
                const float* rp = &s_in[ci][r + ky][colb];
                float4 v4 = *(const float4*)rp;
                float2 v2 = *(const float2*)(rp + 4);
                a[ky][0] = v4.x; a[ky][1] = v4.y; a[ky][2] = v4.z; a[ky][3] = v4.w;
                a[ky][4] = v2.x; a[ky][5] = v2.y;
            }
#pragma unroll
            for (int ky = 0; ky < 3; ++ky)
#pragma unroll
                for (int kx = 0; kx < 3; ++kx) {
                    const float* wp = &s_w[ci][ky * 3 + kx][wv * 8];
                    float4 w0 = *(const float4*)wp;
                    float4 w1 = *(const float4*)(wp + 4);
                    float wr[8] = {w0.x, w0.y, w0.z, w0.w, w1.x, w1.y, w1.z, w1.w};
#pragma unroll
                    for (int o = 0; o < 8; ++o)
#pragma unroll
                        for (int p = 0; p < 4; ++p)
                            acc[o][p] = fmaf(a[ky][kx + p], wr[o], acc[o][p]);
                }
        }
        __syncthreads();
    }

    // ---- epilogue ----
    const int ocbase = ocb * 32 + wv * 8;
    float* outb = out + (size_t)b * COUT * HW;
#pragma unroll
    for (int o = 0; o < 8; ++o) {
        int oc = ocbase + o;
        if (oc < COUT) {
            float bi = bias[oc];
            float4 v;
            v.x = acc[o][0] + bi; v.y = acc[o][1] + bi;
            v.z = acc[o][2] + bi; v.w = acc[o][3] + bi;
            if (RELU_OUT) {
                v.x = fmaxf(v.x, 0.f); v.y = fmaxf(v.y, 0.f);
                v.z = fmaxf(v.z, 0.f); v.w = fmaxf(v.w, 0.f);
            }
            *(float4*)&outb[(size_t)oc * HW + (size_t)(row0 + r) * W + col0 + colb] = v;
        }
    }
}

// ---------------- DCN v2 (C=256, K=3, pad=1), relu output ----------------
#define DCK 2
__global__ __launch_bounds__(512, 2)
void dcn_kernel(const float* __restrict__ f, const float* __restrict__ om,
                const float* __restrict__ wt, const float* __restrict__ bias,
                float* __restrict__ out, int H, int W)
{
    // grid: x = W/16, y = H/8, z = B. block = 512.
    __shared__ float4 s_bw[9][128];        // mask-premultiplied bilinear weights (0 if invalid)
    __shared__ int2   s_ba[9][128];        // raw (y0, x0)
    __shared__ float  s_s[DCK][9][128];    // sampled values
    __shared__ float  s_w[DCK][9][256];    // weights [ci][k][oc]

    const int tid  = threadIdx.x;
    const int b    = blockIdx.z;
    const int row0 = blockIdx.y * 8;
    const int col0 = blockIdx.x * 16;
    const size_t HW = (size_t)H * W;
    const float* omb = om + (size_t)b * 27 * HW;

    // ---- precompute bilinear metadata (once per block) ----
    for (int idx = tid; idx < 9 * 128; idx += 512) {
        int k  = idx >> 7;
        int px = idx & 127;
        int y  = row0 + (px >> 4);
        int x  = col0 + (px & 15);
        size_t pp = (size_t)y * W + x;
        float dy = omb[(size_t)(2 * k) * HW + pp];
        float dx = omb[(size_t)(2 * k + 1) * HW + pp];
        float mr = omb[(size_t)(18 + k) * HW + pp];
        float mk = 1.f / (1.f + expf(-mr));
        float ys = (float)(y - 1 + k / 3) + dy;
        float xs = (float)(x - 1 + k % 3) + dx;
        float y0f = floorf(ys), x0f = floorf(xs);
        float wy1 = ys - y0f, wx1 = xs - x0f;
        float wy0 = 1.f - wy1, wx0 = 1.f - wx1;
        int y0 = (int)y0f, x0 = (int)x0f;
        bool vy0 = (y0 >= 0) && (y0 < H);
        bool vy1 = (y0 + 1 >= 0) && (y0 + 1 < H);
        bool vx0 = (x0 >= 0) && (x0 < W);
        bool vx1 = (x0 + 1 >= 0) && (x0 + 1 < W);
        float4 w4;
        w4.x = (vy0 && vx0) ? wy0 * wx0 * mk : 0.f;
        w4.y = (vy0 && vx1) ? wy0 * wx1 * mk : 0.f;
        w4.z = (vy1 && vx0) ? wy1 * wx0 * mk : 0.f;
        w4.w = (vy1 && vx1) ? wy1 * wx1 * mk : 0.f;
        s_bw[k][px] = w4;
        s_ba[k][px] = make_int2(y0, x0);
    }
    __syncthreads();

    const int lane = tid & 63;
    const int wv   = tid >> 6;      // 0..7 -> oc group of 32
    const int px0  = lane << 1;
    const float* fb = f + (size_t)b * 256 * HW;
    float* s_w_flat = &s_w[0][0][0];

    float acc[32][2];
#pragma unroll
    for (int o = 0; o < 32; ++o) { acc[o][0] = 0.f; acc[o][1] = 0.f; }

    for (int c0 = 0; c0 < 256; c0 += DCK) {
        // ---- stage weights (transposed layout: coalesced) ----
        for (int idx = tid; idx < DCK * 9 * 256; idx += 512) {
            s_w_flat[idx] = wt[(size_t)c0 * 2304 + idx];
        }
        // ---- stage samples ----
        for (int idx = tid; idx < DCK * 9 * 128; idx += 512) {
            int ci  = idx / 1152;
            int rem = idx - ci * 1152;
            int k   = rem >> 7;
            int px  = rem & 127;
            const float* fp = fb + (size_t)(c0 + ci) * HW;
            float4 w4 = s_bw[k][px];
            int2  a2  = s_ba[k][px];
            int y0 = a2.x, x0 = a2.y;
            int y0c = min(max(y0, 0), H - 1), y1c = min(max(y0 + 1, 0), H - 1);
            int x0c = min(max(x0, 0), W - 1), x1c = min(max(x0 + 1, 0), W - 1);
            float v = w4.x * fp[(size_t)y0c * W + x0c] + w4.y * fp[(size_t)y0c * W + x1c]
                    + w4.z * fp[(size_t)y1c * W + x0c] + w4.w * fp[(size_t)y1c * W + x1c];
            s_s[ci][k][px] = v;
        }
        __syncthreads();

#pragma unroll
        for (int ci = 0; ci < DCK; ++ci) {
#pragma unroll
            for (int k = 0; k < 9; ++k) {
                float2 sv = *(const float2*)&s_s[ci][k][px0];
                const float* wp = &s_w[ci][k][wv * 32];
#pragma unroll
                for (int o8 = 0; o8 < 8; ++o8) {
                    float4 wq = *(const float4*)(wp + o8 * 4);
                    acc[o8 * 4 + 0][0] = fmaf(sv.x, wq.x, acc[o8 * 4 + 0][0]);
                    acc[o8 * 4 + 0][1] = fmaf(sv.y, wq.x, acc[o8 * 4 + 0][1]);
                    acc[o8 * 4 + 1][0] = fmaf(sv.x, wq.y, acc[o8 * 4 + 1][0]);
                    acc[o8 * 4 + 1][1] = fmaf(sv.y, wq.y, acc[o8 * 4 + 1][1]);
                    acc[o8 * 4 + 2][0] = fmaf(sv.x, wq.z, acc[o8 * 4 + 2][0]);
                    acc[o8 * 4 + 2][1] = fmaf(sv.y, wq.z, acc[o8 * 4 + 2][1]);
                    acc[o8 * 4 + 3][0] = fmaf(sv.x, wq.w, acc[o8 * 4 + 3][0]);
                    acc[o8 * 4 + 3][1] = fmaf(sv.y, wq.w, acc[o8 * 4 + 3][1]);
                }
            }
        }
        __syncthreads();
    }

    // ---- epilogue: bias + relu ----
    int y = row0 + (px0 >> 4);
    int x = col0 + (px0 & 15);
    float* ob = out + (size_t)b * 256 * HW + (size_t)y * W + x;
#pragma unroll
    for (int o = 0; o < 32; ++o) {
        int oc = wv * 32 + o;
        float bi = bias[oc];
        float2 v2;
        v2.x = fmaxf(acc[o][0] + bi, 0.f);
        v2.y = fmaxf(acc[o][1] + bi, 0.f);
        *(float2*)&ob[(size_t)oc * HW] = v2;
    }
}

// ---------------- 1x1 conv: 256 -> 2 ----------------
__global__ __launch_bounds__(256, 4)
void conv1x1_kernel(const float* __restrict__ in, const float* __restrict__ w,
                    const float* __restrict__ bias, float* __restrict__ out,
                    int B, int HW)
{
    __shared__ float sw[2][256];
    for (int i = threadIdx.x; i < 512; i += 256) sw[i >> 8][i & 255] = w[i];
    __syncthreads();
    int pix = blockIdx.x * 256 + threadIdx.x;
    int b = pix / HW;
    int p = pix - b * HW;
    const float* ip = in + (size_t)b * 256 * HW + p;
    float a0 = 0.f, a1 = 0.f;
    for (int ci = 0; ci < 256; ++ci) {
        float v = ip[(size_t)ci * HW];
        a0 = fmaf(v, sw[0][ci], a0);
        a1 = fmaf(v, sw[1][ci], a1);
    }
    out[(size_t)b * 2 * HW + p]      = a0 + bias[0];
    out[(size_t)b * 2 * HW + HW + p] = a1 + bias[1];
}

// ---------------- host launch ----------------
extern "C" void kernel_launch(void* const* d_in, const int* in_sizes, int n_in,
                              void* d_out, int out_size, void* d_ws, size_t ws_size,
                              hipStream_t stream) {
    const float* x     = (const float*)d_in[0];
    const float* votes = (const float*)d_in[1];
    const float* w1    = (const float*)d_in[2];
    const float* b1    = (const float*)d_in[3];
    const float* w_off = (const float*)d_in[4];
    const float* b_off = (const float*)d_in[5];
    const float* w_dcn = (const float*)d_in[6];
    const float* b_dcn = (const float*)d_in[7];
    const float* w2    = (const float*)d_in[8];
    const float* b2    = (const float*)d_in[9];
    const float* w3    = (const float*)d_in[10];
    const float* b3    = (const float*)d_in[11];
    const float* w4    = (const float*)d_in[12];
    const float* b4    = (const float*)d_in[13];
    float* outp = (float*)d_out;

    const int B = 2, C = 256, H = 128, W = 128;
    const size_t HW = (size_t)H * W;
    const size_t featN = (size_t)B * C * HW;     // 8,388,608

    float* ws    = (float*)d_ws;
    float* slotA = ws;                            // t1 -> t3
    float* slotOM = slotA + featN;                // om (B*27*HW = 884736)
    float* slotC = slotOM + (size_t)B * 27 * HW;  // t2 -> h
    float* wT    = slotC + featN;                 // reused transposed-weight scratch (589824)

    dim3 convGrid(W / CTW, H / CTH, B * 8);       // 256-out convs: 8 oc-blocks
    dim3 convGridOff(W / CTW, H / CTH, B * 1);    // 27-out conv
    int wtransBlocks256 = (256 * 256 * 9 + 255) / 256;  // 2304
    int wtransBlocksOff = (27 * 256 * 9 + 255) / 256;   // 243

    // conv1: t1 = relu(conv(relu(votes), w1, b1))
    wtrans_kernel<<<wtransBlocks256, 256, 0, stream>>>(w1, wT, 256, 256);
    conv3x3_kernel<256, true, 1><<<convGrid, 256, 0, stream>>>(votes, nullptr, wT, b1, slotA, 256, 8, H, W);

    // conv_off: om = conv(t1, w_off, b_off)
    wtrans_kernel<<<wtransBlocksOff, 256, 0, stream>>>(w_off, wT, 27, 256);
    conv3x3_kernel<256, false, 0><<<convGridOff, 256, 0, stream>>>(slotA, nullptr, wT, b_off, slotOM, 27, 1, H, W);

    // dcn: t2 = relu(dcn(t1, om, w_dcn, b_dcn))
    wtrans_kernel<<<wtransBlocks256, 256, 0, stream>>>(w_dcn, wT, 256, 256);
    dcn_kernel<<<dim3(W / 16, H / 8, B), 512, 0, stream>>>(slotA, slotOM, wT, b_dcn, slotC, H, W);

    // conv2: t3 = conv(t2, w2, b2)   (no relu)
    wtrans_kernel<<<wtransBlocks256, 256, 0, stream>>>(w2, wT, 256, 256);
    conv3x3_kernel<256, false, 0><<<convGrid, 256, 0, stream>>>(slotC, nullptr, wT, b2, slotA, 256, 8, H, W);

    // conv3: h = relu(conv(t3 * x, w3, b3))
    wtrans_kernel<<<wtransBlocks256, 256, 0, stream>>>(w3, wT, 256, 256);
    conv3x3_kernel<256, true, 2><<<convGrid, 256, 0, stream>>>(slotA, x, wT, b3, slotC, 256, 8, H, W);

    // conv4: out = conv1x1(h, w4, b4)
    conv1x1_kernel<<<(B * (int)HW) / 256, 256, 0, stream>>>(slotC, w4, b4, outp, B, (int)HW);
}

// Round 2
// 2563.902 us; speedup vs baseline: 1.2722x; 1.2722x over previous
//
#include <hip/hip_runtime.h>
#include <math.h>

typedef short short8 __attribute__((ext_vector_type(8)));
typedef float f32x4 __attribute__((ext_vector_type(4)));
typedef unsigned short ushort_t;

__device__ inline ushort_t f2bf(float f) {
    unsigned u = __builtin_bit_cast(unsigned, f);
    u = (u + 0x7fffu + ((u >> 16) & 1u)) >> 16;   // round-to-nearest-even
    return (ushort_t)u;
}

// ---------------- weight packer: w[oc][ci][tap] fp32 -> bf16 B-fragment order ----------------
// wpk layout: [ocblk][kstep 72][nfrag NF][lane 64][8 bf16]
// conv order: kstep = cc*9 + t ; dcn order: kstep = t*8 + cc   (cc = ci/32, t = tap)
__global__ __launch_bounds__(256)
void wpack_kernel(const float* __restrict__ w, ushort_t* __restrict__ wpk,
                  int COUT, int NF, int dcnOrder) {
    int T = blockIdx.x * 256 + threadIdx.x;
    int lane = T & 63;
    int rest = T >> 6;
    int n = rest % NF; rest /= NF;
    int kstep = rest % 72;
    int ocblk = rest / 72;
    int t, cc;
    if (dcnOrder) { t = kstep >> 3; cc = kstep & 7; }
    else          { cc = kstep / 9; t = kstep - cc * 9; }
    int oc = ocblk * (16 * NF) + n * 16 + (lane & 15);
    int kk = (lane >> 4) * 8;
    short8 sv;
#pragma unroll
    for (int j = 0; j < 8; ++j) {
        int ci = cc * 32 + kk + j;
        float val = (oc < COUT) ? w[((size_t)oc * 256 + ci) * 9 + t] : 0.f;
        sv[j] = (short)f2bf(val);
    }
    *(short8*)&wpk[(size_t)T * 8] = sv;
}

// ---------------- MFMA implicit-GEMM 3x3 conv, pad=1 ----------------
// block: 256 thr = 4 waves; tile 256 px (8y x 32x) x 64 oc; K = 8 ci-chunks x 9 taps x 32
#define CTH 8
#define CTW 32
__global__ __launch_bounds__(256, 2)
void conv_mfma_kernel(const float* __restrict__ in, const float* __restrict__ in2,
                      const ushort_t* __restrict__ wpk, const float* __restrict__ bias,
                      float* __restrict__ out, int COUT, int NOCBLK,
                      int FUSE, int RELU, int H, int W)
{
    __shared__ __align__(16) short s_a[10 * 34 * 40];                 // halo [y][x][40ci-slots]
    __shared__ __align__(16) union { short b[9 * 2048]; float o[32 * 260]; } s_u;

    const int tid  = threadIdx.x;
    const int lane = tid & 63;
    const int wv   = tid >> 6;
    const int hi   = lane >> 4;
    const int lo   = lane & 15;
    const int bz   = blockIdx.z;
    const int b    = bz / NOCBLK;
    const int ocblk = bz % NOCBLK;
    const int y0 = blockIdx.y * CTH;
    const int x0 = blockIdx.x * CTW;
    const size_t HW = (size_t)H * W;
    const float* inb  = in + (size_t)b * 256 * HW;
    const float* in2b = (FUSE == 2) ? in2 + (size_t)b * 256 * HW : nullptr;

    int ym[4], xm[4];
#pragma unroll
    for (int m = 0; m < 4; ++m) {
        int px = (wv * 4 + m) * 16 + lo;
        ym[m] = px >> 5; xm[m] = px & 31;
    }

    f32x4 acc[4][4];
#pragma unroll
    for (int m = 0; m < 4; ++m)
#pragma unroll
        for (int n = 0; n < 4; ++n) acc[m][n] = (f32x4){0.f, 0.f, 0.f, 0.f};

    for (int cc = 0; cc < 8; ++cc) {
        // ---- stage halo (2 ci per item, packed bf16 pair) ----
        for (int idx = tid; idx < 10 * 34 * 16; idx += 256) {
            int cp  = idx / 340;
            int rem = idx - cp * 340;
            int yy  = rem / 34;
            int xx  = rem - yy * 34;
            int gy = y0 - 1 + yy, gx = x0 - 1 + xx;
            float v0 = 0.f, v1 = 0.f;
            if ((unsigned)gy < (unsigned)H && (unsigned)gx < (unsigned)W) {
                size_t gbase = (size_t)(cc * 32 + cp * 2) * HW + (size_t)gy * W + gx;
                v0 = inb[gbase]; v1 = inb[gbase + HW];
                if (FUSE == 1) { v0 = fmaxf(v0, 0.f); v1 = fmaxf(v1, 0.f); }
                else if (FUSE == 2) { v0 *= in2b[gbase]; v1 *= in2b[gbase + HW]; }
            }
            unsigned pk = (unsigned)f2bf(v0) | ((unsigned)f2bf(v1) << 16);
            *(unsigned*)&s_a[(yy * 34 + xx) * 40 + cp * 2] = pk;
        }
        // ---- stage B: 9 ksteps x 2048 shorts, fragment-linear ----
        {
            const ushort_t* src = wpk + (size_t)(ocblk * 72 + cc * 9) * 2048;
#pragma unroll
            for (int q = 0; q < 9; ++q)
                *(short8*)&s_u.b[q * 2048 + tid * 8] = *(const short8*)&src[q * 2048 + tid * 8];
        }
        __syncthreads();

        for (int t = 0; t < 9; ++t) {
            int ky = t / 3, kx = t - ky * 3;
            short8 bf[4];
#pragma unroll
            for (int n = 0; n < 4; ++n)
                bf[n] = *(const short8*)&s_u.b[t * 2048 + (n * 64 + lane) * 8];
            short8 af[4];
#pragma unroll
            for (int m = 0; m < 4; ++m)
                af[m] = *(const short8*)&s_a[((ym[m] + ky) * 34 + (xm[m] + kx)) * 40 + hi * 8];
#pragma unroll
            for (int m = 0; m < 4; ++m)
#pragma unroll
                for (int n = 0; n < 4; ++n)
                    acc[m][n] = __builtin_amdgcn_mfma_f32_16x16x32_bf16(af[m], bf[n], acc[m][n], 0, 0, 0);
        }
        __syncthreads();
    }

    // ---- epilogue: LDS transpose, coalesced float4 stores ----
    float* outb = out + (size_t)b * COUT * HW;
    for (int p = 0; p < 2; ++p) {
#pragma unroll
        for (int half = 0; half < 2; ++half) {
            int n = p * 2 + half;
            int ocg = ocblk * 64 + n * 16 + lo;
            float bv = (ocg < COUT) ? bias[ocg] : 0.f;
            int ocr = half * 16 + lo;
#pragma unroll
            for (int m = 0; m < 4; ++m) {
                int pxb = (wv * 4 + m) * 16 + hi * 4;
#pragma unroll
                for (int r = 0; r < 4; ++r) {
                    float v = acc[m][n][r] + bv;
                    if (RELU) v = fmaxf(v, 0.f);
                    s_u.o[ocr * 260 + pxb + r] = v;
                }
            }
        }
        __syncthreads();
#pragma unroll
        for (int i = 0; i < 8; ++i) {
            int it = i * 256 + tid;
            int ocr = it >> 6;
            int g = it & 63;
            int px = g * 4;
            int oc = ocblk * 64 + p * 32 + ocr;
            if (oc < COUT) {
                float4 v = *(const float4*)&s_u.o[ocr * 260 + px];
                int yy = px >> 5, xx = px & 31;
                *(float4*)&outb[(size_t)oc * HW + (size_t)(y0 + yy) * W + x0 + xx] = v;
            }
        }
        __syncthreads();
    }
}

// ---------------- DCN v2 with fused bilinear sampling + MFMA ----------------
// block: 256 thr = 4 waves; tile 256 px x 128 oc (ocblk in {0,1}); relu epilogue
__global__ __launch_bounds__(256, 2)
void dcn_mfma_kernel(const float* __restrict__ f, const float* __restrict__ om,
                     const ushort_t* __restrict__ wpk, const float* __restrict__ bias,
                     float* __restrict__ out, int H, int W)
{
    __shared__ __align__(16) short s_a[256 * 40];                     // [px][40ci-slots]
    __shared__ __align__(16) union { short b[4096]; float o[32 * 260]; } s_u;

    const int tid  = threadIdx.x;
    const int lane = tid & 63;
    const int wv   = tid >> 6;
    const int hi   = lane >> 4;
    const int lo   = lane & 15;
    const int px0  = blockIdx.x * 256;
    const int ocblk = blockIdx.y;
    const int b    = blockIdx.z;
    const size_t HW = (size_t)H * W;

    int a_off[4];
#pragma unroll
    for (int m = 0; m < 4; ++m)
        a_off[m] = ((wv * 4 + m) * 16 + lo) * 40 + hi * 8;

    f32x4 acc[4][8];
#pragma unroll
    for (int m = 0; m < 4; ++m)
#pragma unroll
        for (int n = 0; n < 8; ++n) acc[m][n] = (f32x4){0.f, 0.f, 0.f, 0.f};

    const int px  = px0 + tid;
    const int py  = px >> 7;          // W = 128
    const int pxx = px & 127;
    const float* omb = om + (size_t)b * 27 * HW;
    const float* fb  = f + (size_t)b * 256 * HW;

    for (int t = 0; t < 9; ++t) {
        // ---- per-pixel tap metadata (registers) ----
        float dy = omb[(size_t)(2 * t) * HW + px];
        float dx = omb[(size_t)(2 * t + 1) * HW + px];
        float mr = omb[(size_t)(18 + t) * HW + px];
        float mk = 1.f / (1.f + expf(-mr));
        float ys = (float)(py - 1 + t / 3) + dy;
        float xs = (float)(pxx - 1 + t % 3) + dx;
        float y0f = floorf(ys), x0f = floorf(xs);
        float wy1 = ys - y0f, wx1 = xs - x0f;
        float wy0 = 1.f - wy1, wx0 = 1.f - wx1;
        int yi = (int)y0f, xi = (int)x0f;
        bool vy0 = (yi >= 0) && (yi < H);
        bool vy1 = (yi + 1 >= 0) && (yi + 1 < H);
        bool vx0 = (xi >= 0) && (xi < W);
        bool vx1 = (xi + 1 >= 0) && (xi + 1 < W);
        float w00 = (vy0 && vx0) ? wy0 * wx0 * mk : 0.f;
        float w01 = (vy0 && vx1) ? wy0 * wx1 * mk : 0.f;
        float w10 = (vy1 && vx0) ? wy1 * wx0 * mk : 0.f;
        float w11 = (vy1 && vx1) ? wy1 * wx1 * mk : 0.f;
        int y0c = min(max(yi, 0), H - 1), y1c = min(max(yi + 1, 0), H - 1);
        int x0c = min(max(xi, 0), W - 1), x1c = min(max(xi + 1, 0), W - 1);
        int o00 = y0c * W + x0c, o01 = y0c * W + x1c;
        int o10 = y1c * W + x0c, o11 = y1c * W + x1c;

        for (int cc = 0; cc < 8; ++cc) {
            // ---- sample 32 ci for this thread's pixel ----
            const float* fp = fb + (size_t)(cc * 32) * HW;
#pragma unroll
            for (int sg = 0; sg < 4; ++sg) {
                short8 sv;
#pragma unroll
                for (int e = 0; e < 8; ++e) {
                    const float* q = fp + (size_t)(sg * 8 + e) * HW;
                    float v = w00 * q[o00] + w01 * q[o01] + w10 * q[o10] + w11 * q[o11];
                    sv[e] = (short)f2bf(v);
                }
                *(short8*)&s_a[tid * 40 + sg * 8] = sv;
            }
            // ---- stage B (4096 shorts) ----
            const ushort_t* src = wpk + (size_t)(ocblk * 72 + t * 8 + cc) * 4096;
            *(short8*)&s_u.b[tid * 8]        = *(const short8*)&src[tid * 8];
            *(short8*)&s_u.b[2048 + tid * 8] = *(const short8*)&src[2048 + tid * 8];
            __syncthreads();

            short8 bf[8];
#pragma unroll
            for (int n = 0; n < 8; ++n)
                bf[n] = *(const short8*)&s_u.b[(n * 64 + lane) * 8];
#pragma unroll
            for (int m = 0; m < 4; ++m) {
                short8 av = *(const short8*)&s_a[a_off[m]];
#pragma unroll
                for (int n = 0; n < 8; ++n)
                    acc[m][n] = __builtin_amdgcn_mfma_f32_16x16x32_bf16(av, bf[n], acc[m][n], 0, 0, 0);
            }
            __syncthreads();
        }
    }

    // ---- epilogue: bias + relu, LDS transpose, coalesced stores ----
    float* outb = out + (size_t)b * 256 * HW;
    for (int p = 0; p < 4; ++p) {
#pragma unroll
        for (int half = 0; half < 2; ++half) {
            int n = p * 2 + half;
            int oc = ocblk * 128 + n * 16 + lo;
            float bv = bias[oc];
            int ocr = half * 16 + lo;
#pragma unroll
            for (int m = 0; m < 4; ++m) {
                int pxb = (wv * 4 + m) * 16 + hi * 4;
#pragma unroll
                for (int r = 0; r < 4; ++r)
                    s_u.o[ocr * 260 + pxb + r] = fmaxf(acc[m][n][r] + bv, 0.f);
            }
        }
        __syncthreads();
#pragma unroll
        for (int i = 0; i < 8; ++i) {
            int it = i * 256 + tid;
            int ocr = it >> 6;
            int g = it & 63;
            int oc = ocblk * 128 + p * 32 + ocr;
            float4 v = *(const float4*)&s_u.o[ocr * 260 + g * 4];
            *(float4*)&outb[(size_t)oc * HW + px0 + g * 4] = v;
        }
        __syncthreads();
    }
}

// ---------------- 1x1 conv: 256 -> 2 ----------------
__global__ __launch_bounds__(256, 4)
void conv1x1_kernel(const float* __restrict__ in, const float* __restrict__ w,
                    const float* __restrict__ bias, float* __restrict__ out,
                    int B, int HW)
{
    __shared__ float sw[2][256];
    for (int i = threadIdx.x; i < 512; i += 256) sw[i >> 8][i & 255] = w[i];
    __syncthreads();
    int pix = blockIdx.x * 256 + threadIdx.x;
    int b = pix / HW;
    int p = pix - b * HW;
    const float* ip = in + (size_t)b * 256 * HW + p;
    float a0 = 0.f, a1 = 0.f;
    for (int ci = 0; ci < 256; ++ci) {
        float v = ip[(size_t)ci * HW];
        a0 = fmaf(v, sw[0][ci], a0);
        a1 = fmaf(v, sw[1][ci], a1);
    }
    out[(size_t)b * 2 * HW + p]      = a0 + bias[0];
    out[(size_t)b * 2 * HW + HW + p] = a1 + bias[1];
}

// ---------------- host launch ----------------
extern "C" void kernel_launch(void* const* d_in, const int* in_sizes, int n_in,
                              void* d_out, int out_size, void* d_ws, size_t ws_size,
                              hipStream_t stream) {
    const float* x     = (const float*)d_in[0];
    const float* votes = (const float*)d_in[1];
    const float* w1    = (const float*)d_in[2];
    const float* b1    = (const float*)d_in[3];
    const float* w_off = (const float*)d_in[4];
    const float* b_off = (const float*)d_in[5];
    const float* w_dcn = (const float*)d_in[6];
    const float* b_dcn = (const float*)d_in[7];
    const float* w2    = (const float*)d_in[8];
    const float* b2    = (const float*)d_in[9];
    const float* w3    = (const float*)d_in[10];
    const float* b3    = (const float*)d_in[11];
    const float* w4    = (const float*)d_in[12];
    const float* b4    = (const float*)d_in[13];
    float* outp = (float*)d_out;

    const int B = 2, H = 128, W = 128;
    const size_t HW = (size_t)H * W;
    const size_t featN = (size_t)B * 256 * HW;

    float* ws     = (float*)d_ws;
    float* slotA  = ws;
    float* slotOM = slotA + featN;
    float* slotC  = slotOM + (size_t)B * 27 * HW;
    ushort_t* wpk = (ushort_t*)(slotC + featN);   // 589824 bf16 = 1.18 MB

    dim3 convGrid(W / CTW, H / CTH, B * 4);
    dim3 convGridOff(W / CTW, H / CTH, B * 1);

    // conv1: t1 = relu(conv(relu(votes), w1, b1))
    wpack_kernel<<<(4 * 72 * 4 * 64) / 256, 256, 0, stream>>>(w1, wpk, 256, 4, 0);
    conv_mfma_kernel<<<convGrid, 256, 0, stream>>>(votes, nullptr, wpk, b1, slotA, 256, 4, 1, 1, H, W);

    // conv_off: om = conv(t1, w_off, b_off)
    wpack_kernel<<<(1 * 72 * 4 * 64) / 256, 256, 0, stream>>>(w_off, wpk, 27, 4, 0);
    conv_mfma_kernel<<<convGridOff, 256, 0, stream>>>(slotA, nullptr, wpk, b_off, slotOM, 27, 1, 0, 0, H, W);

    // dcn: t2 = relu(dcn(t1, om, w_dcn, b_dcn))
    wpack_kernel<<<(2 * 72 * 8 * 64) / 256, 256, 0, stream>>>(w_dcn, wpk, 256, 8, 1);
    dcn_mfma_kernel<<<dim3((int)(HW / 256), 2, B), 256, 0, stream>>>(slotA, slotOM, wpk, b_dcn, slotC, H, W);

    // conv2: t3 = conv(t2, w2, b2)
    wpack_kernel<<<(4 * 72 * 4 * 64) / 256, 256, 0, stream>>>(w2, wpk, 256, 4, 0);
    conv_mfma_kernel<<<convGrid, 256, 0, stream>>>(slotC, nullptr, wpk, b2, slotA, 256, 4, 0, 0, H, W);

    // conv3: h = relu(conv(t3 * x, w3, b3))
    wpack_kernel<<<(4 * 72 * 4 * 64) / 256, 256, 0, stream>>>(w3, wpk, 256, 4, 0);
    conv_mfma_kernel<<<convGrid, 256, 0, stream>>>(slotA, x, wpk, b3, slotC, 256, 4, 2, 1, H, W);

    // conv4: out = conv1x1(h, w4, b4)
    conv1x1_kernel<<<(int)((B * HW) / 256), 256, 0, stream>>>(slotC, w4, b4, outp, B, (int)HW);
}

// Round 3
// 602.009 us; speedup vs baseline: 5.4182x; 4.2589x over previous
//
#include <hip/hip_runtime.h>
#include <math.h>

typedef short short8 __attribute__((ext_vector_type(8)));
typedef float f32x4 __attribute__((ext_vector_type(4)));
typedef unsigned int uint4v __attribute__((ext_vector_type(4)));
typedef unsigned short ushort_t;

__device__ inline ushort_t f2bf(float f) {
    unsigned u = __builtin_bit_cast(unsigned, f);
    u = (u + 0x7fffu + ((u >> 16) & 1u)) >> 16;   // round-to-nearest-even
    return (ushort_t)u;
}

// ---------------- weight packer: w[oc][ci][tap] fp32 -> bf16 B-fragment order ----------------
// wpk layout: [ocblk][kstep 72][nfrag NF][lane 64][8 bf16]
// conv order: kstep = cc*9 + t ; dcn order: kstep = t*8 + cc   (cc = ci/32, t = tap)
__global__ __launch_bounds__(256)
void wpack_kernel(const float* __restrict__ w, ushort_t* __restrict__ wpk,
                  int COUT, int NF, int dcnOrder) {
    int T = blockIdx.x * 256 + threadIdx.x;
    int lane = T & 63;
    int rest = T >> 6;
    int n = rest % NF; rest /= NF;
    int kstep = rest % 72;
    int ocblk = rest / 72;
    int t, cc;
    if (dcnOrder) { t = kstep >> 3; cc = kstep & 7; }
    else          { cc = kstep / 9; t = kstep - cc * 9; }
    int oc = ocblk * (16 * NF) + n * 16 + (lane & 15);
    int kk = (lane >> 4) * 8;
    short8 sv;
#pragma unroll
    for (int j = 0; j < 8; ++j) {
        int ci = cc * 32 + kk + j;
        float val = (oc < COUT) ? w[((size_t)oc * 256 + ci) * 9 + t] : 0.f;
        sv[j] = (short)f2bf(val);
    }
    *(short8*)&wpk[(size_t)T * 8] = sv;
}

// ---------------- NCHW fp32 -> NHWC bf16 transpose (for DCN gather) ----------------
// grid: (HW/64, 256/64, B), block 256
__global__ __launch_bounds__(256)
void nhwc_kernel(const float* __restrict__ in, ushort_t* __restrict__ out, int HW) {
    __shared__ short s[64 * 66];
    const int tid = threadIdx.x;
    const int px0 = blockIdx.x * 64;
    const int ci0 = blockIdx.y * 64;
    const int b   = blockIdx.z;
    const float* inb = in + (size_t)b * 256 * HW;
#pragma unroll
    for (int rep = 0; rep < 16; ++rep) {
        int ci_local = rep * 4 + (tid >> 6);
        int px_local = tid & 63;
        float v = inb[(size_t)(ci0 + ci_local) * HW + px0 + px_local];
        s[px_local * 66 + ci_local] = (short)f2bf(v);
    }
    __syncthreads();
    ushort_t* ob = out + (size_t)b * HW * 256;
#pragma unroll
    for (int rep = 0; rep < 2; ++rep) {
        int c = rep * 256 + tid;
        int px_local = c >> 3;
        int cl = (c & 7) * 8;
        short8 v = *(const short8*)&s[px_local * 66 + cl];
        *(short8*)&ob[(size_t)(px0 + px_local) * 256 + ci0 + cl] = v;
    }
}

// ---------------- MFMA implicit-GEMM 3x3 conv, pad=1 (unchanged from round 2) ----------------
#define CTH 8
#define CTW 32
__global__ __launch_bounds__(256, 2)
void conv_mfma_kernel(const float* __restrict__ in, const float* __restrict__ in2,
                      const ushort_t* __restrict__ wpk, const float* __restrict__ bias,
                      float* __restrict__ out, int COUT, int NOCBLK,
                      int FUSE, int RELU, int H, int W)
{
    __shared__ __align__(16) short s_a[10 * 34 * 40];                 // halo [y][x][40ci-slots]
    __shared__ __align__(16) union { short b[9 * 2048]; float o[32 * 260]; } s_u;

    const int tid  = threadIdx.x;
    const int lane = tid & 63;
    const int wv   = tid >> 6;
    const int hi   = lane >> 4;
    const int lo   = lane & 15;
    const int bz   = blockIdx.z;
    const int b    = bz / NOCBLK;
    const int ocblk = bz % NOCBLK;
    const int y0 = blockIdx.y * CTH;
    const int x0 = blockIdx.x * CTW;
    const size_t HW = (size_t)H * W;
    const float* inb  = in + (size_t)b * 256 * HW;
    const float* in2b = (FUSE == 2) ? in2 + (size_t)b * 256 * HW : nullptr;

    int ym[4], xm[4];
#pragma unroll
    for (int m = 0; m < 4; ++m) {
        int px = (wv * 4 + m) * 16 + lo;
        ym[m] = px >> 5; xm[m] = px & 31;
    }

    f32x4 acc[4][4];
#pragma unroll
    for (int m = 0; m < 4; ++m)
#pragma unroll
        for (int n = 0; n < 4; ++n) acc[m][n] = (f32x4){0.f, 0.f, 0.f, 0.f};

    for (int cc = 0; cc < 8; ++cc) {
        for (int idx = tid; idx < 10 * 34 * 16; idx += 256) {
            int cp  = idx / 340;
            int rem = idx - cp * 340;
            int yy  = rem / 34;
            int xx  = rem - yy * 34;
            int gy = y0 - 1 + yy, gx = x0 - 1 + xx;
            float v0 = 0.f, v1 = 0.f;
            if ((unsigned)gy < (unsigned)H && (unsigned)gx < (unsigned)W) {
                size_t gbase = (size_t)(cc * 32 + cp * 2) * HW + (size_t)gy * W + gx;
                v0 = inb[gbase]; v1 = inb[gbase + HW];
                if (FUSE == 1) { v0 = fmaxf(v0, 0.f); v1 = fmaxf(v1, 0.f); }
                else if (FUSE == 2) { v0 *= in2b[gbase]; v1 *= in2b[gbase + HW]; }
            }
            unsigned pk = (unsigned)f2bf(v0) | ((unsigned)f2bf(v1) << 16);
            *(unsigned*)&s_a[(yy * 34 + xx) * 40 + cp * 2] = pk;
        }
        {
            const ushort_t* src = wpk + (size_t)(ocblk * 72 + cc * 9) * 2048;
#pragma unroll
            for (int q = 0; q < 9; ++q)
                *(short8*)&s_u.b[q * 2048 + tid * 8] = *(const short8*)&src[q * 2048 + tid * 8];
        }
        __syncthreads();

        for (int t = 0; t < 9; ++t) {
            int ky = t / 3, kx = t - ky * 3;
            short8 bf[4];
#pragma unroll
            for (int n = 0; n < 4; ++n)
                bf[n] = *(const short8*)&s_u.b[t * 2048 + (n * 64 + lane) * 8];
            short8 af[4];
#pragma unroll
            for (int m = 0; m < 4; ++m)
                af[m] = *(const short8*)&s_a[((ym[m] + ky) * 34 + (xm[m] + kx)) * 40 + hi * 8];
#pragma unroll
            for (int m = 0; m < 4; ++m)
#pragma unroll
                for (int n = 0; n < 4; ++n)
                    acc[m][n] = __builtin_amdgcn_mfma_f32_16x16x32_bf16(af[m], bf[n], acc[m][n], 0, 0, 0);
        }
        __syncthreads();
    }

    float* outb = out + (size_t)b * COUT * HW;
    for (int p = 0; p < 2; ++p) {
#pragma unroll
        for (int half = 0; half < 2; ++half) {
            int n = p * 2 + half;
            int ocg = ocblk * 64 + n * 16 + lo;
            float bv = (ocg < COUT) ? bias[ocg] : 0.f;
            int ocr = half * 16 + lo;
#pragma unroll
            for (int m = 0; m < 4; ++m) {
                int pxb = (wv * 4 + m) * 16 + hi * 4;
#pragma unroll
                for (int r = 0; r < 4; ++r) {
                    float v = acc[m][n][r] + bv;
                    if (RELU) v = fmaxf(v, 0.f);
                    s_u.o[ocr * 260 + pxb + r] = v;
                }
            }
        }
        __syncthreads();
#pragma unroll
        for (int i = 0; i < 8; ++i) {
            int it = i * 256 + tid;
            int ocr = it >> 6;
            int g = it & 63;
            int px = g * 4;
            int oc = ocblk * 64 + p * 32 + ocr;
            if (oc < COUT) {
                float4 v = *(const float4*)&s_u.o[ocr * 260 + px];
                int yy = px >> 5, xx = px & 31;
                *(float4*)&outb[(size_t)oc * HW + (size_t)(y0 + yy) * W + x0 + xx] = v;
            }
        }
        __syncthreads();
    }
}

// ---------------- DCN v2: NHWC bf16 gather + fused MFMA, 128px x 256oc per block ----------------
__device__ inline void corner8(uint4v u, float w, float* sv) {
#pragma unroll
    for (int j = 0; j < 4; ++j) {
        unsigned a = u[j];
        sv[2 * j]     = fmaf(w, __builtin_bit_cast(float, a << 16), sv[2 * j]);
        sv[2 * j + 1] = fmaf(w, __builtin_bit_cast(float, a & 0xffff0000u), sv[2 * j + 1]);
    }
}

__global__ __launch_bounds__(512, 2)
void dcn_mfma_kernel(const ushort_t* __restrict__ ft, const float* __restrict__ om,
                     const ushort_t* __restrict__ wpk, const float* __restrict__ bias,
                     float* __restrict__ out, int H, int W)
{
    __shared__ __align__(16) short s_a[128 * 40];    // [px][40ci-slots]
    __shared__ __align__(16) float s_o[32 * 132];    // epilogue staging

    const int tid  = threadIdx.x;
    const int lane = tid & 63;
    const int wv   = tid >> 6;
    const int hi   = lane >> 4;
    const int lo   = lane & 15;
    const int px0  = blockIdx.x * 128;
    const int b    = blockIdx.y;
    const size_t HW = (size_t)H * W;

    const int pxl = tid & 127;      // sampling pixel (local)
    const int q   = tid >> 7;       // ci-quarter (8 ci each)
    const int px  = px0 + pxl;
    const int py  = px / W;
    const int pxx = px - py * W;

    const float* omb = om + (size_t)b * 27 * HW;
    const ushort_t* fb = ft + (size_t)b * HW * 256;
    const int nb = (wv >> 2) * 8;   // n-frag base (oc half)

    int a_off[2];
#pragma unroll
    for (int m = 0; m < 2; ++m)
        a_off[m] = ((wv & 3) * 32 + m * 16 + lo) * 40 + hi * 8;

    f32x4 acc[2][8];
#pragma unroll
    for (int m = 0; m < 2; ++m)
#pragma unroll
        for (int n = 0; n < 8; ++n) acc[m][n] = (f32x4){0.f, 0.f, 0.f, 0.f};

    for (int t = 0; t < 9; ++t) {
        // ---- per-pixel tap metadata (registers; duplicated across ci-quarters) ----
        float dy = omb[(size_t)(2 * t) * HW + px];
        float dx = omb[(size_t)(2 * t + 1) * HW + px];
        float mr = omb[(size_t)(18 + t) * HW + px];
        float mk = 1.f / (1.f + expf(-mr));
        float ys = (float)(py - 1 + t / 3) + dy;
        float xs = (float)(pxx - 1 + t % 3) + dx;
        float y0f = floorf(ys), x0f = floorf(xs);
        float wy1 = ys - y0f, wx1 = xs - x0f;
        float wy0 = 1.f - wy1, wx0 = 1.f - wx1;
        int yi = (int)y0f, xi = (int)x0f;
        bool vy0 = (yi >= 0) && (yi < H);
        bool vy1 = (yi + 1 >= 0) && (yi + 1 < H);
        bool vx0 = (xi >= 0) && (xi < W);
        bool vx1 = (xi + 1 >= 0) && (xi + 1 < W);
        float w00 = (vy0 && vx0) ? wy0 * wx0 * mk : 0.f;
        float w01 = (vy0 && vx1) ? wy0 * wx1 * mk : 0.f;
        float w10 = (vy1 && vx0) ? wy1 * wx0 * mk : 0.f;
        float w11 = (vy1 && vx1) ? wy1 * wx1 * mk : 0.f;
        int y0c = min(max(yi, 0), H - 1), y1c = min(max(yi + 1, 0), H - 1);
        int x0c = min(max(xi, 0), W - 1), x1c = min(max(xi + 1, 0), W - 1);
        size_t o00 = (size_t)(y0c * W + x0c) * 256, o01 = (size_t)(y0c * W + x1c) * 256;
        size_t o10 = (size_t)(y1c * W + x0c) * 256, o11 = (size_t)(y1c * W + x1c) * 256;

        for (int cc = 0; cc < 8; ++cc) {
            // ---- gather 8 ci for this thread's pixel (16B vector loads, NHWC) ----
            const ushort_t* pc = fb + cc * 32 + q * 8;
            uint4v u00 = *(const uint4v*)(pc + o00);
            uint4v u01 = *(const uint4v*)(pc + o01);
            uint4v u10 = *(const uint4v*)(pc + o10);
            uint4v u11 = *(const uint4v*)(pc + o11);
            // ---- B fragments direct from global (fragment-linear, L2-resident) ----
            short8 bfr[8];
            {
                const ushort_t* bsrc = wpk + ((size_t)(t * 8 + cc) * 16 + nb) * 512 + lane * 8;
#pragma unroll
                for (int n = 0; n < 8; ++n)
                    bfr[n] = *(const short8*)(bsrc + n * 512);
            }
            float sv[8] = {0.f, 0.f, 0.f, 0.f, 0.f, 0.f, 0.f, 0.f};
            corner8(u00, w00, sv); corner8(u01, w01, sv);
            corner8(u10, w10, sv); corner8(u11, w11, sv);
            unsigned pk[4];
#pragma unroll
            for (int j = 0; j < 4; ++j)
                asm("v_cvt_pk_bf16_f32 %0, %1, %2" : "=v"(pk[j]) : "v"(sv[2 * j]), "v"(sv[2 * j + 1]));

            __syncthreads();   // previous iteration's A-frag reads done
            *(uint4v*)&s_a[pxl * 40 + q * 8] = (uint4v){pk[0], pk[1], pk[2], pk[3]};
            __syncthreads();   // s_a visible

#pragma unroll
            for (int m = 0; m < 2; ++m) {
                short8 av = *(const short8*)&s_a[a_off[m]];
#pragma unroll
                for (int n = 0; n < 8; ++n)
                    acc[m][n] = __builtin_amdgcn_mfma_f32_16x16x32_bf16(av, bfr[n], acc[m][n], 0, 0, 0);
            }
        }
    }

    // ---- epilogue: bias + relu, LDS transpose, coalesced stores ----
    __syncthreads();
    float* outb = out + (size_t)b * 256 * HW;
    for (int p = 0; p < 8; ++p) {
        if ((wv >> 2) == (p >> 2)) {
#pragma unroll
            for (int h2 = 0; h2 < 2; ++h2) {
                int n = (p & 3) * 2 + h2;
                int oc = p * 32 + h2 * 16 + lo;
                float bv = bias[oc];
                int ocr = h2 * 16 + lo;
#pragma unroll
                for (int m = 0; m < 2; ++m) {
                    int pxb = (wv & 3) * 32 + m * 16 + hi * 4;
#pragma unroll
                    for (int r = 0; r < 4; ++r)
                        s_o[ocr * 132 + pxb + r] = fmaxf(acc[m][n][r] + bv, 0.f);
                }
            }
        }
        __syncthreads();
#pragma unroll
        for (int i = 0; i < 2; ++i) {
            int c = i * 512 + tid;
            int ocr = c >> 5;
            int g = c & 31;
            float4 v = *(const float4*)&s_o[ocr * 132 + g * 4];
            *(float4*)&outb[(size_t)(p * 32 + ocr) * HW + px0 + g * 4] = v;
        }
        __syncthreads();
    }
}

// ---------------- 1x1 conv: 256 -> 2 ----------------
__global__ __launch_bounds__(256, 4)
void conv1x1_kernel(const float* __restrict__ in, const float* __restrict__ w,
                    const float* __restrict__ bias, float* __restrict__ out,
                    int B, int HW)
{
    __shared__ float sw[2][256];
    for (int i = threadIdx.x; i < 512; i += 256) sw[i >> 8][i & 255] = w[i];
    __syncthreads();
    int pix = blockIdx.x * 256 + threadIdx.x;
    int b = pix / HW;
    int p = pix - b * HW;
    const float* ip = in + (size_t)b * 256 * HW + p;
    float a0 = 0.f, a1 = 0.f;
    for (int ci = 0; ci < 256; ++ci) {
        float v = ip[(size_t)ci * HW];
        a0 = fmaf(v, sw[0][ci], a0);
        a1 = fmaf(v, sw[1][ci], a1);
    }
    out[(size_t)b * 2 * HW + p]      = a0 + bias[0];
    out[(size_t)b * 2 * HW + HW + p] = a1 + bias[1];
}

// ---------------- host launch ----------------
extern "C" void kernel_launch(void* const* d_in, const int* in_sizes, int n_in,
                              void* d_out, int out_size, void* d_ws, size_t ws_size,
                              hipStream_t stream) {
    const float* x     = (const float*)d_in[0];
    const float* votes = (const float*)d_in[1];
    const float* w1    = (const float*)d_in[2];
    const float* b1    = (const float*)d_in[3];
    const float* w_off = (const float*)d_in[4];
    const float* b_off = (const float*)d_in[5];
    const float* w_dcn = (const float*)d_in[6];
    const float* b_dcn = (const float*)d_in[7];
    const float* w2    = (const float*)d_in[8];
    const float* b2    = (const float*)d_in[9];
    const float* w3    = (const float*)d_in[10];
    const float* b3    = (const float*)d_in[11];
    const float* w4    = (const float*)d_in[12];
    const float* b4    = (const float*)d_in[13];
    float* outp = (float*)d_out;

    const int B = 2, H = 128, W = 128;
    const size_t HW = (size_t)H * W;
    const size_t featN = (size_t)B * 256 * HW;

    float* ws     = (float*)d_ws;
    float* slotA  = ws;
    float* slotOM = slotA + featN;
    float* slotC  = slotOM + (size_t)B * 27 * HW;
    ushort_t* wpk = (ushort_t*)(slotC + featN);        // 589824 bf16
    ushort_t* ft  = wpk + 589824;                      // NHWC bf16 t1 (16.8 MB)

    dim3 convGrid(W / CTW, H / CTH, B * 4);
    dim3 convGridOff(W / CTW, H / CTH, B * 1);

    // conv1: t1 = relu(conv(relu(votes), w1, b1))
    wpack_kernel<<<(4 * 72 * 4 * 64) / 256, 256, 0, stream>>>(w1, wpk, 256, 4, 0);
    conv_mfma_kernel<<<convGrid, 256, 0, stream>>>(votes, nullptr, wpk, b1, slotA, 256, 4, 1, 1, H, W);

    // t1 -> NHWC bf16 for DCN gather
    nhwc_kernel<<<dim3((int)(HW / 64), 4, B), 256, 0, stream>>>(slotA, ft, (int)HW);

    // conv_off: om = conv(t1, w_off, b_off)
    wpack_kernel<<<(1 * 72 * 4 * 64) / 256, 256, 0, stream>>>(w_off, wpk, 27, 4, 0);
    conv_mfma_kernel<<<convGridOff, 256, 0, stream>>>(slotA, nullptr, wpk, b_off, slotOM, 27, 1, 0, 0, H, W);

    // dcn: t2 = relu(dcn(t1, om, w_dcn, b_dcn))
    wpack_kernel<<<(1 * 72 * 16 * 64) / 256, 256, 0, stream>>>(w_dcn, wpk, 256, 16, 1);
    dcn_mfma_kernel<<<dim3((int)(HW / 128), B), 512, 0, stream>>>(ft, slotOM, wpk, b_dcn, slotC, H, W);

    // conv2: t3 = conv(t2, w2, b2)
    wpack_kernel<<<(4 * 72 * 4 * 64) / 256, 256, 0, stream>>>(w2, wpk, 256, 4, 0);
    conv_mfma_kernel<<<convGrid, 256, 0, stream>>>(slotC, nullptr, wpk, b2, slotA, 256, 4, 0, 0, H, W);

    // conv3: h = relu(conv(t3 * x, w3, b3))
    wpack_kernel<<<(4 * 72 * 4 * 64) / 256, 256, 0, stream>>>(w3, wpk, 256, 4, 0);
    conv_mfma_kernel<<<convGrid, 256, 0, stream>>>(slotA, x, wpk, b3, slotC, 256, 4, 2, 1, H, W);

    // conv4: out = conv1x1(h, w4, b4)
    conv1x1_kernel<<<(int)((B * HW) / 256), 256, 0, stream>>>(slotC, w4, b4, outp, B, (int)HW);
}

// Round 4
// 346.646 us; speedup vs baseline: 9.4095x; 1.7367x over previous
//
#include <hip/hip_runtime.h>
#include <math.h>

typedef short short8 __attribute__((ext_vector_type(8)));
typedef float f32x4 __attribute__((ext_vector_type(4)));
typedef unsigned int uint4v __attribute__((ext_vector_type(4)));
typedef unsigned short ushort_t;

__device__ inline ushort_t f2bf(float f) {
    unsigned u = __builtin_bit_cast(unsigned, f);
    u = (u + 0x7fffu + ((u >> 16) & 1u)) >> 16;   // RNE
    return (ushort_t)u;
}
__device__ inline float bf2f(ushort_t u) {
    return __builtin_bit_cast(float, (unsigned)u << 16);
}
__device__ inline void gload_lds16(const ushort_t* g, short* l) {
    __builtin_amdgcn_global_load_lds((const __attribute__((address_space(1))) unsigned int*)g,
                                     (__attribute__((address_space(3))) unsigned int*)l, 16, 0, 0);
}

// ---------------- zero page init ----------------
__global__ __launch_bounds__(256)
void zeroinit_kernel(ushort_t* zp) { zp[threadIdx.x] = 0; }

// ---------------- NCHW fp32 -> NHWC bf16 (optional relu) ----------------
template<bool RELU>
__global__ __launch_bounds__(256)
void nhwc_cvt_kernel(const float* __restrict__ in, ushort_t* __restrict__ out) {
    __shared__ short s[64 * 66];
    const int tid = threadIdx.x;
    const int px0 = blockIdx.x * 64;
    const int ci0 = blockIdx.y * 64;
    const int b   = blockIdx.z;
    const float* inb = in + (size_t)b * 256 * 16384;
#pragma unroll
    for (int rep = 0; rep < 16; ++rep) {
        int cl = rep * 4 + (tid >> 6);
        int pl = tid & 63;
        float v = inb[(size_t)(ci0 + cl) * 16384 + px0 + pl];
        if (RELU) v = fmaxf(v, 0.f);
        s[pl * 66 + cl] = (short)f2bf(v);
    }
    __syncthreads();
    ushort_t* ob = out + (size_t)b * 16384 * 256;
#pragma unroll
    for (int rep = 0; rep < 2; ++rep) {
        int c = rep * 256 + tid;
        int pl = c >> 3;
        int cl = (c & 7) * 8;
        *(short8*)&ob[(size_t)(px0 + pl) * 256 + ci0 + cl] = *(const short8*)&s[pl * 66 + cl];
    }
}

// ---------------- weight packer: w[oc][ci][tap] fp32 -> bf16 B-frag order ----------------
// layout: [kstep = t*8+cc][nfrag NF][lane 64][8 bf16]
__global__ __launch_bounds__(256)
void wpack_kernel(const float* __restrict__ w, ushort_t* __restrict__ wpk,
                  int COUT, int NF) {
    int T = blockIdx.x * 256 + threadIdx.x;
    int lane = T & 63;
    int rest = T >> 6;
    int n = rest % NF;
    int kstep = rest / NF;          // 0..71
    int t = kstep >> 3, cc = kstep & 7;
    int oc = n * 16 + (lane & 15);
    int kk = (lane >> 4) * 8;
    short8 sv;
#pragma unroll
    for (int j = 0; j < 8; ++j) {
        int ci = cc * 32 + kk + j;
        float val = (oc < COUT) ? w[((size_t)oc * 256 + ci) * 9 + t] : 0.f;
        sv[j] = (short)f2bf(val);
    }
    *(short8*)&wpk[(size_t)T * 8] = sv;
}

// ---------------- MFMA implicit-GEMM 3x3 conv, NHWC bf16 in/out ----------------
// block: 512 thr = 8 waves; tile 128 px (4y x 32x) x OUTC oc; grid (4, 32, B)
// EPI: 0 = bias, 1 = bias+relu, 2 = (bias+v)*x
template<int OUTC, int EPI>
__global__ __launch_bounds__(512, 2)
void conv_mfma_kernel(const ushort_t* __restrict__ in, const ushort_t* __restrict__ wpk,
                      const float* __restrict__ bias, int coutReal,
                      const ushort_t* __restrict__ xin, ushort_t* __restrict__ outp,
                      const ushort_t* __restrict__ zp)
{
    constexpr int NF = OUTC / 16;
    constexpr int NN = (NF < 4) ? NF : 4;
    constexpr int PITCH = OUTC + 4;
    union SM { short a[2][256 * 32]; float e[32 * PITCH]; };
    __shared__ __align__(16) SM sm;

    const int tid  = threadIdx.x;
    const int lane = tid & 63;
    const int wv   = tid >> 6;
    const int hi   = lane >> 4;
    const int lo   = lane & 15;
    const int pxg  = wv & 1;      // px half (rows 2pxg..2pxg+1)
    const int wn   = wv >> 1;     // oc quarter
    const int wnu  = __builtin_amdgcn_readfirstlane(wn);
    const int x0 = blockIdx.x * 32;
    const int y0 = blockIdx.y * 4;
    const int b  = blockIdx.z;
    const ushort_t* inb = in + (size_t)b * 16384 * 256;

    // staging source (2 rounds x 16B); swizzled ci-chunk on the SOURCE side
    const ushort_t* sptr[2];
    int sstep[2];
#pragma unroll
    for (int r = 0; r < 2; ++r) {
        int g = r * 512 + tid;
        int px = g >> 2, slot = g & 3;
        int hy = px / 34, hx = px - hy * 34;
        int gy = y0 - 1 + hy, gx = x0 - 1 + hx;
        bool ok = (px < 204) && ((unsigned)gy < 128u) && ((unsigned)gx < 128u);
        int kk = (px ^ (px >> 2)) & 3;
        sptr[r] = ok ? (inb + (size_t)((gy << 7) + gx) * 256 + ((slot ^ kk) << 3))
                     : (zp + (slot << 3));
        sstep[r] = ok ? 32 : 0;
    }

    int pxh_base[4];
#pragma unroll
    for (int m = 0; m < 4; ++m)
        pxh_base[m] = (2 * pxg + (m >> 1)) * 34 + (m & 1) * 16 + lo;

    f32x4 acc[4][NN];
#pragma unroll
    for (int m = 0; m < 4; ++m)
#pragma unroll
        for (int n = 0; n < NN; ++n) acc[m][n] = (f32x4){0.f, 0.f, 0.f, 0.f};

    // prologue: stage cc=0 into buf 0
#pragma unroll
    for (int r = 0; r < 2; ++r)
        gload_lds16(sptr[r], &sm.a[0][(r * 512 + wv * 64) * 8]);
    __syncthreads();

    for (int cc = 0; cc < 8; ++cc) {
        const int buf = cc & 1;
        if (cc < 7) {
#pragma unroll
            for (int r = 0; r < 2; ++r)
                gload_lds16(sptr[r] + (size_t)(cc + 1) * sstep[r],
                            &sm.a[buf ^ 1][(r * 512 + wv * 64) * 8]);
        }
        if (NF >= 4 || wnu == 0) {
#pragma unroll
            for (int t = 0; t < 9; ++t) {
                const int ky = t / 3, kx = t % 3;
                short8 bf[NN];
#pragma unroll
                for (int n = 0; n < NN; ++n)
                    bf[n] = *(const short8*)&wpk[((size_t)((t * 8 + cc) * NF + wnu * 4 + n) * 64 + lane) * 8];
                short8 af[4];
#pragma unroll
                for (int m = 0; m < 4; ++m) {
                    int ph = pxh_base[m] + ky * 34 + kx;
                    int off = ph * 32 + ((hi ^ ((ph ^ (ph >> 2)) & 3)) << 3);
                    af[m] = *(const short8*)&sm.a[buf][off];
                }
#pragma unroll
                for (int m = 0; m < 4; ++m)
#pragma unroll
                    for (int n = 0; n < NN; ++n)
                        acc[m][n] = __builtin_amdgcn_mfma_f32_16x16x32_bf16(af[m], bf[n], acc[m][n], 0, 0, 0);
            }
        }
        __syncthreads();
    }

    // ---- epilogue: [px][oc] f32 staging -> packed bf16 NHWC stores ----
    float br[NN];
#pragma unroll
    for (int n = 0; n < NN; ++n) {
        int oc = wn * 64 + n * 16 + lo;
        br[n] = (oc < coutReal) ? bias[oc] : 0.f;
    }
    const size_t obase = ((size_t)b * 16384 + (size_t)y0 * 128 + x0) * OUTC;
#pragma unroll
    for (int p = 0; p < 4; ++p) {
        if (pxg == (p >> 1) && (NF >= 4 || wnu == 0)) {
#pragma unroll
            for (int mm = 0; mm < 2; ++mm) {
                int m = (p & 1) * 2 + mm;
#pragma unroll
                for (int n = 0; n < NN; ++n)
#pragma unroll
                    for (int r = 0; r < 4; ++r) {
                        int col = mm * 16 + hi * 4 + r;
                        float v = acc[m][n][r] + br[n];
                        if (EPI == 1) v = fmaxf(v, 0.f);
                        sm.e[col * PITCH + wn * 64 + n * 16 + lo] = v;
                    }
            }
        }
        __syncthreads();
        constexpr int CHUNKS = 32 * OUTC / 8;
        for (int c = tid; c < CHUNKS; c += 512) {
            int col = c / (OUTC / 8);
            int ch = c % (OUTC / 8);
            f32x4 v0 = *(const f32x4*)&sm.e[col * PITCH + ch * 8];
            f32x4 v1 = *(const f32x4*)&sm.e[col * PITCH + ch * 8 + 4];
            size_t gidx = obase + ((size_t)p * 128 + col) * OUTC + ch * 8;
            if (EPI == 2) {
                uint4v xu = *(const uint4v*)&xin[gidx];
#pragma unroll
                for (int j = 0; j < 4; ++j) {
                    float xa = bf2f((ushort_t)(xu[j] & 0xffffu));
                    float xb = __builtin_bit_cast(float, xu[j] & 0xffff0000u);
                    if (j < 2) { v0[2 * j] *= xa; v0[2 * j + 1] *= xb; }
                    else       { v1[2 * (j - 2)] *= xa; v1[2 * (j - 2) + 1] *= xb; }
                }
            }
            short8 s;
#pragma unroll
            for (int j = 0; j < 4; ++j) s[j] = (short)f2bf(v0[j]);
#pragma unroll
            for (int j = 0; j < 4; ++j) s[4 + j] = (short)f2bf(v1[j]);
            *(short8*)&outp[gidx] = s;
        }
        __syncthreads();
    }
}

// ---------------- DCN v2: NHWC bf16 gather + fused MFMA ----------------
__device__ inline void corner8(uint4v u, float w, float* sv) {
#pragma unroll
    for (int j = 0; j < 4; ++j) {
        unsigned a = u[j];
        sv[2 * j]     = fmaf(w, __builtin_bit_cast(float, a << 16), sv[2 * j]);
        sv[2 * j + 1] = fmaf(w, __builtin_bit_cast(float, a & 0xffff0000u), sv[2 * j + 1]);
    }
}

__global__ __launch_bounds__(512, 2)
void dcn_mfma_kernel(const ushort_t* __restrict__ ft, const ushort_t* __restrict__ omt,
                     const ushort_t* __restrict__ wpk, const float* __restrict__ bias,
                     ushort_t* __restrict__ outp)
{
    union SM { short a[128 * 32]; float e[16 * 260]; };
    __shared__ __align__(16) SM sm;

    const int tid  = threadIdx.x;
    const int lane = tid & 63;
    const int wv   = tid >> 6;
    const int hi   = lane >> 4;
    const int lo   = lane & 15;
    const int px0  = blockIdx.x * 128;
    const int b    = blockIdx.y;

    const int pxl = tid & 127;
    const int q   = tid >> 7;
    const int px  = px0 + pxl;
    const int py  = px >> 7;
    const int pxx = px & 127;
    const ushort_t* fb  = ft + (size_t)b * 16384 * 256;
    const ushort_t* omb = omt + ((size_t)b * 16384 + px) * 32;
    const int wq  = wv & 3;
    const int wh  = wv >> 2;
    const int whu = __builtin_amdgcn_readfirstlane(wh);

    int a_off[2];
#pragma unroll
    for (int m = 0; m < 2; ++m) {
        int p_ = wq * 32 + m * 16 + lo;
        a_off[m] = p_ * 32 + ((hi ^ ((p_ ^ (p_ >> 2)) & 3)) << 3);
    }
    const int w_off = pxl * 32 + ((q ^ ((pxl ^ (pxl >> 2)) & 3)) << 3);

    f32x4 acc[2][8];
#pragma unroll
    for (int m = 0; m < 2; ++m)
#pragma unroll
        for (int n = 0; n < 8; ++n) acc[m][n] = (f32x4){0.f, 0.f, 0.f, 0.f};

    for (int t = 0; t < 9; ++t) {
        float dy = bf2f(omb[2 * t]);
        float dx = bf2f(omb[2 * t + 1]);
        float mr = bf2f(omb[18 + t]);
        float mk = 1.f / (1.f + expf(-mr));
        float ys = (float)(py - 1 + t / 3) + dy;
        float xs = (float)(pxx - 1 + t % 3) + dx;
        float y0f = floorf(ys), x0f = floorf(xs);
        float wy1 = ys - y0f, wx1 = xs - x0f;
        float wy0 = 1.f - wy1, wx0 = 1.f - wx1;
        int yi = (int)y0f, xi = (int)x0f;
        bool vy0 = (yi >= 0) && (yi < 128);
        bool vy1 = (yi + 1 >= 0) && (yi + 1 < 128);
        bool vx0 = (xi >= 0) && (xi < 128);
        bool vx1 = (xi + 1 >= 0) && (xi + 1 < 128);
        float w00 = (vy0 && vx0) ? wy0 * wx0 * mk : 0.f;
        float w01 = (vy0 && vx1) ? wy0 * wx1 * mk : 0.f;
        float w10 = (vy1 && vx0) ? wy1 * wx0 * mk : 0.f;
        float w11 = (vy1 && vx1) ? wy1 * wx1 * mk : 0.f;
        int y0c = min(max(yi, 0), 127), y1c = min(max(yi + 1, 0), 127);
        int x0c = min(max(xi, 0), 127), x1c = min(max(xi + 1, 0), 127);
        size_t o00 = (size_t)((y0c << 7) + x0c) * 256, o01 = (size_t)((y0c << 7) + x1c) * 256;
        size_t o10 = (size_t)((y1c << 7) + x0c) * 256, o11 = (size_t)((y1c << 7) + x1c) * 256;

        for (int cc = 0; cc < 8; ++cc) {
            const ushort_t* pc = fb + cc * 32 + q * 8;
            uint4v u00 = *(const uint4v*)(pc + o00);
            uint4v u01 = *(const uint4v*)(pc + o01);
            uint4v u10 = *(const uint4v*)(pc + o10);
            uint4v u11 = *(const uint4v*)(pc + o11);
            short8 bfr[8];
            {
                const ushort_t* bsrc = wpk + ((size_t)((t * 8 + cc) * 16 + whu * 8) * 64 + lane) * 8;
#pragma unroll
                for (int n = 0; n < 8; ++n)
                    bfr[n] = *(const short8*)(bsrc + (size_t)n * 512);
            }
            float sv[8] = {0.f, 0.f, 0.f, 0.f, 0.f, 0.f, 0.f, 0.f};
            corner8(u00, w00, sv); corner8(u01, w01, sv);
            corner8(u10, w10, sv); corner8(u11, w11, sv);
            unsigned pk[4];
#pragma unroll
            for (int j = 0; j < 4; ++j)
                asm("v_cvt_pk_bf16_f32 %0, %1, %2" : "=v"(pk[j]) : "v"(sv[2 * j]), "v"(sv[2 * j + 1]));

            __syncthreads();
            *(uint4v*)&sm.a[w_off] = (uint4v){pk[0], pk[1], pk[2], pk[3]};
            __syncthreads();

#pragma unroll
            for (int m = 0; m < 2; ++m) {
                short8 av = *(const short8*)&sm.a[a_off[m]];
#pragma unroll
                for (int n = 0; n < 8; ++n)
                    acc[m][n] = __builtin_amdgcn_mfma_f32_16x16x32_bf16(av, bfr[n], acc[m][n], 0, 0, 0);
            }
        }
    }

    // ---- epilogue: NHWC bf16 ----
    float br[8];
#pragma unroll
    for (int n = 0; n < 8; ++n) br[n] = bias[wh * 128 + n * 16 + lo];
    __syncthreads();
#pragma unroll
    for (int p = 0; p < 8; ++p) {
        if (wq == (p >> 1)) {
            int m = p & 1;
#pragma unroll
            for (int n = 0; n < 8; ++n)
#pragma unroll
                for (int r = 0; r < 4; ++r)
                    sm.e[(hi * 4 + r) * 260 + wh * 128 + n * 16 + lo] = fmaxf(acc[m][n][r] + br[n], 0.f);
        }
        __syncthreads();
        {
            int pl = tid >> 5, ch = tid & 31;
            f32x4 v0 = *(const f32x4*)&sm.e[pl * 260 + ch * 8];
            f32x4 v1 = *(const f32x4*)&sm.e[pl * 260 + ch * 8 + 4];
            short8 s;
#pragma unroll
            for (int j = 0; j < 4; ++j) s[j] = (short)f2bf(v0[j]);
#pragma unroll
            for (int j = 0; j < 4; ++j) s[4 + j] = (short)f2bf(v1[j]);
            *(short8*)&outp[((size_t)b * 16384 + px0 + p * 16 + pl) * 256 + ch * 8] = s;
        }
        __syncthreads();
    }
}

// ---------------- 1x1 conv: 256 -> 2, NHWC bf16 in, NCHW fp32 out ----------------
__global__ __launch_bounds__(256)
void conv1x1_kernel(const ushort_t* __restrict__ in, const float* __restrict__ w,
                    const float* __restrict__ bias, float* __restrict__ out)
{
    __shared__ float sw[512];
    for (int i = threadIdx.x; i < 512; i += 256) sw[i] = w[i];
    __syncthreads();
    int px = blockIdx.x * 256 + threadIdx.x;   // 0..32767
    int b = px >> 14, p = px & 16383;
    const ushort_t* ip = in + (size_t)px * 256;
    float a0 = 0.f, a1 = 0.f;
#pragma unroll
    for (int ch = 0; ch < 32; ++ch) {
        uint4v u = *(const uint4v*)&ip[ch * 8];
#pragma unroll
        for (int j = 0; j < 4; ++j) {
            int ci = ch * 8 + 2 * j;
            float fa = __builtin_bit_cast(float, u[j] << 16);
            float fb = __builtin_bit_cast(float, u[j] & 0xffff0000u);
            a0 = fmaf(fa, sw[ci], a0);      a1 = fmaf(fa, sw[256 + ci], a1);
            a0 = fmaf(fb, sw[ci + 1], a0);  a1 = fmaf(fb, sw[256 + ci + 1], a1);
        }
    }
    out[(size_t)b * 2 * 16384 + p]         = a0 + bias[0];
    out[(size_t)b * 2 * 16384 + 16384 + p] = a1 + bias[1];
}

// ---------------- host launch ----------------
extern "C" void kernel_launch(void* const* d_in, const int* in_sizes, int n_in,
                              void* d_out, int out_size, void* d_ws, size_t ws_size,
                              hipStream_t stream) {
    const float* x     = (const float*)d_in[0];
    const float* votes = (const float*)d_in[1];
    const float* w1    = (const float*)d_in[2];
    const float* b1    = (const float*)d_in[3];
    const float* w_off = (const float*)d_in[4];
    const float* b_off = (const float*)d_in[5];
    const float* w_dcn = (const float*)d_in[6];
    const float* b_dcn = (const float*)d_in[7];
    const float* w2    = (const float*)d_in[8];
    const float* b2    = (const float*)d_in[9];
    const float* w3    = (const float*)d_in[10];
    const float* b3    = (const float*)d_in[11];
    const float* w4    = (const float*)d_in[12];
    const float* b4    = (const float*)d_in[13];
    float* outp = (float*)d_out;

    const int B = 2;
    const size_t featN = (size_t)B * 16384 * 256;   // 8,388,608 shorts per feature

    ushort_t* ws   = (ushort_t*)d_ws;
    ushort_t* t1   = ws;
    ushort_t* t2   = t1 + featN;
    ushort_t* aN   = t2 + featN;          // relu(votes) nhwc, later g
    ushort_t* xN   = aN + featN;          // x nhwc, later h
    ushort_t* om   = xN + featN;          // B*16384*32
    ushort_t* wpk1 = om + (size_t)B * 16384 * 32;
    ushort_t* wpkO = wpk1 + 589824;
    ushort_t* wpkD = wpkO + 73728;
    ushort_t* wpk2 = wpkD + 589824;
    ushort_t* wpk3 = wpk2 + 589824;
    ushort_t* zp   = wpk3 + 589824;

    zeroinit_kernel<<<1, 256, 0, stream>>>(zp);
    nhwc_cvt_kernel<true><<<dim3(256, 4, B), 256, 0, stream>>>(votes, aN);
    nhwc_cvt_kernel<false><<<dim3(256, 4, B), 256, 0, stream>>>(x, xN);
    wpack_kernel<<<288, 256, 0, stream>>>(w1, wpk1, 256, 16);
    wpack_kernel<<<36, 256, 0, stream>>>(w_off, wpkO, 27, 2);
    wpack_kernel<<<288, 256, 0, stream>>>(w_dcn, wpkD, 256, 16);
    wpack_kernel<<<288, 256, 0, stream>>>(w2, wpk2, 256, 16);
    wpack_kernel<<<288, 256, 0, stream>>>(w3, wpk3, 256, 16);

    dim3 cg(4, 32, B);
    // conv1: t1 = relu(conv(relu(votes), w1, b1))
    conv_mfma_kernel<256, 1><<<cg, 512, 0, stream>>>(aN, wpk1, b1, 256, nullptr, t1, zp);
    // conv_off: om = conv(t1, w_off, b_off)   (27 ch, padded to 32, NHWC)
    conv_mfma_kernel<32, 0><<<cg, 512, 0, stream>>>(t1, wpkO, b_off, 27, nullptr, om, zp);
    // dcn: t2 = relu(dcn(t1, om, w_dcn, b_dcn))
    dcn_mfma_kernel<<<dim3(128, B), 512, 0, stream>>>(t1, om, wpkD, b_dcn, t2);
    // conv2 + fuse: g = (conv(t2, w2) + b2) * x
    conv_mfma_kernel<256, 2><<<cg, 512, 0, stream>>>(t2, wpk2, b2, 256, xN, aN, zp);
    // conv3: h = relu(conv(g, w3, b3))
    conv_mfma_kernel<256, 1><<<cg, 512, 0, stream>>>(aN, wpk3, b3, 256, nullptr, xN, zp);
    // conv4: out = conv1x1(h, w4, b4)
    conv1x1_kernel<<<128, 256, 0, stream>>>(xN, w4, b4, outp);
}

// Round 5
// 317.021 us; speedup vs baseline: 10.2889x; 1.0934x over previous
//
#include <hip/hip_runtime.h>
#include <math.h>

typedef short short8 __attribute__((ext_vector_type(8)));
typedef float f32x4 __attribute__((ext_vector_type(4)));
typedef unsigned int uint4v __attribute__((ext_vector_type(4)));
typedef unsigned short ushort_t;

__device__ inline ushort_t f2bf(float f) {
    unsigned u = __builtin_bit_cast(unsigned, f);
    u = (u + 0x7fffu + ((u >> 16) & 1u)) >> 16;   // RNE
    return (ushort_t)u;
}
__device__ inline float bf2f(ushort_t u) {
    return __builtin_bit_cast(float, (unsigned)u << 16);
}
__device__ inline void gload_lds16(const ushort_t* g, short* l) {
    __builtin_amdgcn_global_load_lds((const __attribute__((address_space(1))) unsigned int*)g,
                                     (__attribute__((address_space(3))) unsigned int*)l, 16, 0, 0);
}

// ---------------- zero page init ----------------
__global__ __launch_bounds__(256)
void zeroinit_kernel(ushort_t* zp) { zp[threadIdx.x] = 0; }

// ---------------- NCHW fp32 -> NHWC bf16 (optional relu) ----------------
template<bool RELU>
__global__ __launch_bounds__(256)
void nhwc_cvt_kernel(const float* __restrict__ in, ushort_t* __restrict__ out) {
    __shared__ short s[64 * 66];
    const int tid = threadIdx.x;
    const int px0 = blockIdx.x * 64;
    const int ci0 = blockIdx.y * 64;
    const int b   = blockIdx.z;
    const float* inb = in + (size_t)b * 256 * 16384;
#pragma unroll
    for (int rep = 0; rep < 16; ++rep) {
        int cl = rep * 4 + (tid >> 6);
        int pl = tid & 63;
        float v = inb[(size_t)(ci0 + cl) * 16384 + px0 + pl];
        if (RELU) v = fmaxf(v, 0.f);
        s[pl * 66 + cl] = (short)f2bf(v);
    }
    __syncthreads();
    ushort_t* ob = out + (size_t)b * 16384 * 256;
#pragma unroll
    for (int rep = 0; rep < 2; ++rep) {
        int c = rep * 256 + tid;
        int pl = c >> 3;
        int cl = (c & 7) * 8;
        *(short8*)&ob[(size_t)(px0 + pl) * 256 + ci0 + cl] = *(const short8*)&s[pl * 66 + cl];
    }
}

// ---------------- weight packer: w[oc][ci][tap] fp32 -> bf16 B-frag order ----------------
// layout: [kstep = t*8+cc][nfrag NF][lane 64][8 bf16]
__global__ __launch_bounds__(256)
void wpack_kernel(const float* __restrict__ w, ushort_t* __restrict__ wpk,
                  int COUT, int NF) {
    int T = blockIdx.x * 256 + threadIdx.x;
    int lane = T & 63;
    int rest = T >> 6;
    int n = rest % NF;
    int kstep = rest / NF;          // 0..71
    int t = kstep >> 3, cc = kstep & 7;
    int oc = n * 16 + (lane & 15);
    int kk = (lane >> 4) * 8;
    short8 sv;
#pragma unroll
    for (int j = 0; j < 8; ++j) {
        int ci = cc * 32 + kk + j;
        float val = (oc < COUT) ? w[((size_t)oc * 256 + ci) * 9 + t] : 0.f;
        sv[j] = (short)f2bf(val);
    }
    *(short8*)&wpk[(size_t)T * 8] = sv;
}

// ---------------- MFMA implicit-GEMM 3x3 conv, NHWC bf16 in/out ----------------
// block: 512 thr = 8 waves; tile 128 px (4y x 32x) x OUTC oc; grid (4, 32, B)
// EPI: 0 = bias, 1 = bias+relu, 2 = (bias+v)*x
template<int OUTC, int EPI>
__global__ __launch_bounds__(512, 2)
void conv_mfma_kernel(const ushort_t* __restrict__ in, const ushort_t* __restrict__ wpk,
                      const float* __restrict__ bias, int coutReal,
                      const ushort_t* __restrict__ xin, ushort_t* __restrict__ outp,
                      const ushort_t* __restrict__ zp)
{
    constexpr int NF = OUTC / 16;
    constexpr int NN = (NF < 4) ? NF : 4;
    constexpr int PITCH = OUTC + 4;
    union SM { short a[2][256 * 32]; float e[32 * PITCH]; };
    __shared__ __align__(16) SM sm;

    const int tid  = threadIdx.x;
    const int lane = tid & 63;
    const int wv   = tid >> 6;
    const int hi   = lane >> 4;
    const int lo   = lane & 15;
    const int pxg  = wv & 1;      // px half (rows 2pxg..2pxg+1)
    const int wn   = wv >> 1;     // oc quarter
    const int wnu  = __builtin_amdgcn_readfirstlane(wn);
    const int x0 = blockIdx.x * 32;
    const int y0 = blockIdx.y * 4;
    const int b  = blockIdx.z;
    const ushort_t* inb = in + (size_t)b * 16384 * 256;

    // staging source (2 rounds x 16B); swizzled ci-chunk on the SOURCE side
    const ushort_t* sptr[2];
    int sstep[2];
#pragma unroll
    for (int r = 0; r < 2; ++r) {
        int g = r * 512 + tid;
        int px = g >> 2, slot = g & 3;
        int hy = px / 34, hx = px - hy * 34;
        int gy = y0 - 1 + hy, gx = x0 - 1 + hx;
        bool ok = (px < 204) && ((unsigned)gy < 128u) && ((unsigned)gx < 128u);
        int kk = (px ^ (px >> 2)) & 3;
        sptr[r] = ok ? (inb + (size_t)((gy << 7) + gx) * 256 + ((slot ^ kk) << 3))
                     : (zp + (slot << 3));
        sstep[r] = ok ? 32 : 0;
    }

    int pxh_base[4];
#pragma unroll
    for (int m = 0; m < 4; ++m)
        pxh_base[m] = (2 * pxg + (m >> 1)) * 34 + (m & 1) * 16 + lo;

    f32x4 acc[4][NN];
#pragma unroll
    for (int m = 0; m < 4; ++m)
#pragma unroll
        for (int n = 0; n < NN; ++n) acc[m][n] = (f32x4){0.f, 0.f, 0.f, 0.f};

    // prologue: stage cc=0 into buf 0
#pragma unroll
    for (int r = 0; r < 2; ++r)
        gload_lds16(sptr[r], &sm.a[0][(r * 512 + wv * 64) * 8]);
    __syncthreads();

    for (int cc = 0; cc < 8; ++cc) {
        const int buf = cc & 1;
        if (cc < 7) {
#pragma unroll
            for (int r = 0; r < 2; ++r)
                gload_lds16(sptr[r] + (size_t)(cc + 1) * sstep[r],
                            &sm.a[buf ^ 1][(r * 512 + wv * 64) * 8]);
        }
        if (NF >= 4 || wnu == 0) {
#pragma unroll
            for (int t = 0; t < 9; ++t) {
                const int ky = t / 3, kx = t % 3;
                short8 bf[NN];
#pragma unroll
                for (int n = 0; n < NN; ++n)
                    bf[n] = *(const short8*)&wpk[((size_t)((t * 8 + cc) * NF + wnu * 4 + n) * 64 + lane) * 8];
                short8 af[4];
#pragma unroll
                for (int m = 0; m < 4; ++m) {
                    int ph = pxh_base[m] + ky * 34 + kx;
                    int off = ph * 32 + ((hi ^ ((ph ^ (ph >> 2)) & 3)) << 3);
                    af[m] = *(const short8*)&sm.a[buf][off];
                }
#pragma unroll
                for (int m = 0; m < 4; ++m)
#pragma unroll
                    for (int n = 0; n < NN; ++n)
                        acc[m][n] = __builtin_amdgcn_mfma_f32_16x16x32_bf16(af[m], bf[n], acc[m][n], 0, 0, 0);
            }
        }
        __syncthreads();
    }

    // ---- epilogue: [px][oc] f32 staging -> packed bf16 NHWC stores ----
    float br[NN];
#pragma unroll
    for (int n = 0; n < NN; ++n) {
        int oc = wn * 64 + n * 16 + lo;
        br[n] = (oc < coutReal) ? bias[oc] : 0.f;
    }
    const size_t obase = ((size_t)b * 16384 + (size_t)y0 * 128 + x0) * OUTC;
#pragma unroll
    for (int p = 0; p < 4; ++p) {
        if (pxg == (p >> 1) && (NF >= 4 || wnu == 0)) {
#pragma unroll
            for (int mm = 0; mm < 2; ++mm) {
                int m = (p & 1) * 2 + mm;
#pragma unroll
                for (int n = 0; n < NN; ++n)
#pragma unroll
                    for (int r = 0; r < 4; ++r) {
                        int col = mm * 16 + hi * 4 + r;
                        float v = acc[m][n][r] + br[n];
                        if (EPI == 1) v = fmaxf(v, 0.f);
                        sm.e[col * PITCH + wn * 64 + n * 16 + lo] = v;
                    }
            }
        }
        __syncthreads();
        constexpr int CHUNKS = 32 * OUTC / 8;
        for (int c = tid; c < CHUNKS; c += 512) {
            int col = c / (OUTC / 8);
            int ch = c % (OUTC / 8);
            f32x4 v0 = *(const f32x4*)&sm.e[col * PITCH + ch * 8];
            f32x4 v1 = *(const f32x4*)&sm.e[col * PITCH + ch * 8 + 4];
            size_t gidx = obase + ((size_t)p * 128 + col) * OUTC + ch * 8;
            if (EPI == 2) {
                uint4v xu = *(const uint4v*)&xin[gidx];
#pragma unroll
                for (int j = 0; j < 4; ++j) {
                    float xa = bf2f((ushort_t)(xu[j] & 0xffffu));
                    float xb = __builtin_bit_cast(float, xu[j] & 0xffff0000u);
                    if (j < 2) { v0[2 * j] *= xa; v0[2 * j + 1] *= xb; }
                    else       { v1[2 * (j - 2)] *= xa; v1[2 * (j - 2) + 1] *= xb; }
                }
            }
            short8 s;
#pragma unroll
            for (int j = 0; j < 4; ++j) s[j] = (short)f2bf(v0[j]);
#pragma unroll
            for (int j = 0; j < 4; ++j) s[4 + j] = (short)f2bf(v1[j]);
            *(short8*)&outp[gidx] = s;
        }
        __syncthreads();
    }
}

// ---------------- DCN v2: cc-outer/tap-inner, 16x4 px tile, pipelined gather + MFMA ----------------
__device__ inline void corner8(uint4v u, float w, float* sv) {
#pragma unroll
    for (int j = 0; j < 4; ++j) {
        unsigned a = u[j];
        sv[2 * j]     = fmaf(w, __builtin_bit_cast(float, a << 16), sv[2 * j]);
        sv[2 * j + 1] = fmaf(w, __builtin_bit_cast(float, a & 0xffff0000u), sv[2 * j + 1]);
    }
}

__global__ __launch_bounds__(256, 3)
void dcn_mfma_kernel(const ushort_t* __restrict__ ft, const ushort_t* __restrict__ omt,
                     const ushort_t* __restrict__ wpk, const float* __restrict__ bias,
                     ushort_t* __restrict__ outp)
{
    __shared__ __align__(16) f32x4 s_mdw[9][64];     // mask-premultiplied corner weights
    __shared__ unsigned s_mdc[9][64];                // packed clamped coords
    union SM { short a[2][64 * 32]; float e[16 * 260]; };
    __shared__ __align__(16) SM sm;

    const int tid  = threadIdx.x;
    const int lane = tid & 63;
    const int wv   = tid >> 6;
    const int hi   = lane >> 4;
    const int lo   = lane & 15;
    const int x0   = blockIdx.x * 16;
    const int y0   = blockIdx.y * 4;
    const int b    = blockIdx.z;
    const ushort_t* fb = ft + (size_t)b * 16384 * 256;

    // ---- phase 0: per-(px,tap) bilinear metadata into LDS ----
    for (int idx = tid; idx < 576; idx += 256) {
        int t = idx / 64, pl = idx & 63;
        int py = y0 + (pl >> 4), pxx = x0 + (pl & 15);
        const ushort_t* omp = omt + ((size_t)b * 16384 + py * 128 + pxx) * 32;
        float dy = bf2f(omp[2 * t]), dx = bf2f(omp[2 * t + 1]), mr = bf2f(omp[18 + t]);
        float mk = 1.f / (1.f + expf(-mr));
        float ys = (float)(py - 1 + t / 3) + dy;
        float xs = (float)(pxx - 1 + t % 3) + dx;
        float y0f = floorf(ys), x0f = floorf(xs);
        float wy1 = ys - y0f, wx1 = xs - x0f;
        float wy0 = 1.f - wy1, wx0 = 1.f - wx1;
        int yi = (int)y0f, xi = (int)x0f;
        bool vy0 = (yi >= 0) && (yi < 128), vy1 = (yi + 1 >= 0) && (yi + 1 < 128);
        bool vx0 = (xi >= 0) && (xi < 128), vx1 = (xi + 1 >= 0) && (xi + 1 < 128);
        f32x4 w4;
        w4[0] = (vy0 && vx0) ? wy0 * wx0 * mk : 0.f;
        w4[1] = (vy0 && vx1) ? wy0 * wx1 * mk : 0.f;
        w4[2] = (vy1 && vx0) ? wy1 * wx0 * mk : 0.f;
        w4[3] = (vy1 && vx1) ? wy1 * wx1 * mk : 0.f;
        int y0c = min(max(yi, 0), 127), y1c = min(max(yi + 1, 0), 127);
        int x0c = min(max(xi, 0), 127), x1c = min(max(xi + 1, 0), 127);
        s_mdw[t][pl] = w4;
        s_mdc[t][pl] = (unsigned)y0c | ((unsigned)y1c << 8) | ((unsigned)x0c << 16) | ((unsigned)x1c << 24);
    }
    __syncthreads();

    const int pxl = tid & 63;       // sampling pixel (all 64 of tile)
    const int q   = wv;             // ci slice (8 ch of 32)
    const int wm  = wv & 1;         // px half for MFMA
    const int wn  = wv >> 1;        // oc half for MFMA
    const int wnu = __builtin_amdgcn_readfirstlane(wn);
    const int w_off = pxl * 32 + ((q ^ ((pxl ^ (pxl >> 2)) & 3)) << 3);
    int a_off[2];
#pragma unroll
    for (int m = 0; m < 2; ++m) {
        int p_ = (wm * 2 + m) * 16 + lo;
        a_off[m] = p_ * 32 + ((hi ^ ((p_ ^ (p_ >> 2)) & 3)) << 3);
    }

    f32x4 acc[2][8];
#pragma unroll
    for (int m = 0; m < 2; ++m)
#pragma unroll
        for (int n = 0; n < 8; ++n) acc[m][n] = (f32x4){0.f, 0.f, 0.f, 0.f};

    // ---- prologue: sample it=0 (cc=0,t=0) into buf 0 ----
    {
        f32x4 gw = s_mdw[0][pxl];
        unsigned c = s_mdc[0][pxl];
        int yy0 = c & 255, yy1 = (c >> 8) & 255, xx0 = (c >> 16) & 255, xx1 = c >> 24;
        const ushort_t* pc = fb + q * 8;
        uint4v g0 = *(const uint4v*)(pc + ((yy0 << 7) + xx0) * 256);
        uint4v g1 = *(const uint4v*)(pc + ((yy0 << 7) + xx1) * 256);
        uint4v g2 = *(const uint4v*)(pc + ((yy1 << 7) + xx0) * 256);
        uint4v g3 = *(const uint4v*)(pc + ((yy1 << 7) + xx1) * 256);
        float sv[8] = {0.f, 0.f, 0.f, 0.f, 0.f, 0.f, 0.f, 0.f};
        corner8(g0, gw[0], sv); corner8(g1, gw[1], sv);
        corner8(g2, gw[2], sv); corner8(g3, gw[3], sv);
        unsigned pk[4];
#pragma unroll
        for (int j = 0; j < 4; ++j)
            asm("v_cvt_pk_bf16_f32 %0, %1, %2" : "=v"(pk[j]) : "v"(sv[2 * j]), "v"(sv[2 * j + 1]));
        *(uint4v*)&sm.a[0][w_off] = (uint4v){pk[0], pk[1], pk[2], pk[3]};
    }
    __syncthreads();

    // ---- main loop: it = cc*9 + t ----
    for (int it = 0; it < 72; ++it) {
        const int cc = it / 9, t = it - cc * 9;
        const int cur = it & 1;
        // 1. issue next iteration's gathers early
        uint4v n0, n1, n2, n3; f32x4 nw;
        if (it < 71) {
            int itn = it + 1;
            int ccn = itn / 9, tn = itn - ccn * 9;
            nw = s_mdw[tn][pxl];
            unsigned c = s_mdc[tn][pxl];
            int yy0 = c & 255, yy1 = (c >> 8) & 255, xx0 = (c >> 16) & 255, xx1 = c >> 24;
            const ushort_t* pc = fb + ccn * 32 + q * 8;
            n0 = *(const uint4v*)(pc + ((yy0 << 7) + xx0) * 256);
            n1 = *(const uint4v*)(pc + ((yy0 << 7) + xx1) * 256);
            n2 = *(const uint4v*)(pc + ((yy1 << 7) + xx0) * 256);
            n3 = *(const uint4v*)(pc + ((yy1 << 7) + xx1) * 256);
        }
        // 2. B fragments (global, L2-resident, fragment-linear)
        short8 bfr[8];
        {
            const ushort_t* bsrc = wpk + ((size_t)((t * 8 + cc) * 16 + wnu * 8) * 64 + lane) * 8;
#pragma unroll
            for (int n = 0; n < 8; ++n)
                bfr[n] = *(const short8*)(bsrc + (size_t)n * 512);
        }
        // 3. MFMA on current buffer
        short8 af[2];
#pragma unroll
        for (int m = 0; m < 2; ++m)
            af[m] = *(const short8*)&sm.a[cur][a_off[m]];
#pragma unroll
        for (int m = 0; m < 2; ++m)
#pragma unroll
            for (int n = 0; n < 8; ++n)
                acc[m][n] = __builtin_amdgcn_mfma_f32_16x16x32_bf16(af[m], bfr[n], acc[m][n], 0, 0, 0);
        // 4. combine next gathers, write other buffer
        if (it < 71) {
            float sv[8] = {0.f, 0.f, 0.f, 0.f, 0.f, 0.f, 0.f, 0.f};
            corner8(n0, nw[0], sv); corner8(n1, nw[1], sv);
            corner8(n2, nw[2], sv); corner8(n3, nw[3], sv);
            unsigned pk[4];
#pragma unroll
            for (int j = 0; j < 4; ++j)
                asm("v_cvt_pk_bf16_f32 %0, %1, %2" : "=v"(pk[j]) : "v"(sv[2 * j]), "v"(sv[2 * j + 1]));
            *(uint4v*)&sm.a[cur ^ 1][w_off] = (uint4v){pk[0], pk[1], pk[2], pk[3]};
        }
        __syncthreads();
    }

    // ---- epilogue: bias + relu -> NHWC bf16 ----
    float br[8];
#pragma unroll
    for (int n = 0; n < 8; ++n) br[n] = bias[wn * 128 + n * 16 + lo];
#pragma unroll
    for (int p = 0; p < 4; ++p) {
        if (wm == (p >> 1)) {
            int m = p & 1;
#pragma unroll
            for (int n = 0; n < 8; ++n)
#pragma unroll
                for (int r = 0; r < 4; ++r)
                    sm.e[(hi * 4 + r) * 260 + wn * 128 + n * 16 + lo] = fmaxf(acc[m][n][r] + br[n], 0.f);
        }
        __syncthreads();
#pragma unroll
        for (int j = 0; j < 2; ++j) {
            int c2 = j * 256 + tid;
            int pl = c2 >> 5, ch = c2 & 31;
            f32x4 v0 = *(const f32x4*)&sm.e[pl * 260 + ch * 8];
            f32x4 v1 = *(const f32x4*)&sm.e[pl * 260 + ch * 8 + 4];
            short8 s;
#pragma unroll
            for (int jj = 0; jj < 4; ++jj) s[jj] = (short)f2bf(v0[jj]);
#pragma unroll
            for (int jj = 0; jj < 4; ++jj) s[4 + jj] = (short)f2bf(v1[jj]);
            *(short8*)&outp[((size_t)b * 16384 + (size_t)(y0 + p) * 128 + x0 + pl) * 256 + ch * 8] = s;
        }
        __syncthreads();
    }
}

// ---------------- 1x1 conv: 256 -> 2, NHWC bf16 in, NCHW fp32 out ----------------
__global__ __launch_bounds__(256)
void conv1x1_kernel(const ushort_t* __restrict__ in, const float* __restrict__ w,
                    const float* __restrict__ bias, float* __restrict__ out)
{
    __shared__ float sw[512];
    for (int i = threadIdx.x; i < 512; i += 256) sw[i] = w[i];
    __syncthreads();
    int px = blockIdx.x * 256 + threadIdx.x;   // 0..32767
    int b = px >> 14, p = px & 16383;
    const ushort_t* ip = in + (size_t)px * 256;
    float a0 = 0.f, a1 = 0.f;
#pragma unroll
    for (int ch = 0; ch < 32; ++ch) {
        uint4v u = *(const uint4v*)&ip[ch * 8];
#pragma unroll
        for (int j = 0; j < 4; ++j) {
            int ci = ch * 8 + 2 * j;
            float fa = __builtin_bit_cast(float, u[j] << 16);
            float fb = __builtin_bit_cast(float, u[j] & 0xffff0000u);
            a0 = fmaf(fa, sw[ci], a0);      a1 = fmaf(fa, sw[256 + ci], a1);
            a0 = fmaf(fb, sw[ci + 1], a0);  a1 = fmaf(fb, sw[256 + ci + 1], a1);
        }
    }
    out[(size_t)b * 2 * 16384 + p]         = a0 + bias[0];
    out[(size_t)b * 2 * 16384 + 16384 + p] = a1 + bias[1];
}

// ---------------- host launch ----------------
extern "C" void kernel_launch(void* const* d_in, const int* in_sizes, int n_in,
                              void* d_out, int out_size, void* d_ws, size_t ws_size,
                              hipStream_t stream) {
    const float* x     = (const float*)d_in[0];
    const float* votes = (const float*)d_in[1];
    const float* w1    = (const float*)d_in[2];
    const float* b1    = (const float*)d_in[3];
    const float* w_off = (const float*)d_in[4];
    const float* b_off = (const float*)d_in[5];
    const float* w_dcn = (const float*)d_in[6];
    const float* b_dcn = (const float*)d_in[7];
    const float* w2    = (const float*)d_in[8];
    const float* b2    = (const float*)d_in[9];
    const float* w3    = (const float*)d_in[10];
    const float* b3    = (const float*)d_in[11];
    const float* w4    = (const float*)d_in[12];
    const float* b4    = (const float*)d_in[13];
    float* outp = (float*)d_out;

    const int B = 2;
    const size_t featN = (size_t)B * 16384 * 256;   // 8,388,608 shorts per feature

    ushort_t* ws   = (ushort_t*)d_ws;
    ushort_t* t1   = ws;
    ushort_t* t2   = t1 + featN;
    ushort_t* aN   = t2 + featN;          // relu(votes) nhwc, later g
    ushort_t* xN   = aN + featN;          // x nhwc, later h
    ushort_t* om   = xN + featN;          // B*16384*32
    ushort_t* wpk1 = om + (size_t)B * 16384 * 32;
    ushort_t* wpkO = wpk1 + 589824;
    ushort_t* wpkD = wpkO + 73728;
    ushort_t* wpk2 = wpkD + 589824;
    ushort_t* wpk3 = wpk2 + 589824;
    ushort_t* zp   = wpk3 + 589824;

    zeroinit_kernel<<<1, 256, 0, stream>>>(zp);
    nhwc_cvt_kernel<true><<<dim3(256, 4, B), 256, 0, stream>>>(votes, aN);
    nhwc_cvt_kernel<false><<<dim3(256, 4, B), 256, 0, stream>>>(x, xN);
    wpack_kernel<<<288, 256, 0, stream>>>(w1, wpk1, 256, 16);
    wpack_kernel<<<36, 256, 0, stream>>>(w_off, wpkO, 27, 2);
    wpack_kernel<<<288, 256, 0, stream>>>(w_dcn, wpkD, 256, 16);
    wpack_kernel<<<288, 256, 0, stream>>>(w2, wpk2, 256, 16);
    wpack_kernel<<<288, 256, 0, stream>>>(w3, wpk3, 256, 16);

    dim3 cg(4, 32, B);
    // conv1: t1 = relu(conv(relu(votes), w1, b1))
    conv_mfma_kernel<256, 1><<<cg, 512, 0, stream>>>(aN, wpk1, b1, 256, nullptr, t1, zp);
    // conv_off: om = conv(t1, w_off, b_off)   (27 ch, padded to 32, NHWC)
    conv_mfma_kernel<32, 0><<<cg, 512, 0, stream>>>(t1, wpkO, b_off, 27, nullptr, om, zp);
    // dcn: t2 = relu(dcn(t1, om, w_dcn, b_dcn))
    dcn_mfma_kernel<<<dim3(8, 32, B), 256, 0, stream>>>(t1, om, wpkD, b_dcn, t2);
    // conv2 + fuse: g = (conv(t2, w2) + b2) * x
    conv_mfma_kernel<256, 2><<<cg, 512, 0, stream>>>(t2, wpk2, b2, 256, xN, aN, zp);
    // conv3: h = relu(conv(g, w3, b3))
    conv_mfma_kernel<256, 1><<<cg, 512, 0, stream>>>(aN, wpk3, b3, 256, nullptr, xN, zp);
    // conv4: out = conv1x1(h, w4, b4)
    conv1x1_kernel<<<128, 256, 0, stream>>>(xN, w4, b4, outp);
}